// Round 2
// baseline (3931.473 us; speedup 1.0000x reference)
//
#include <hip/hip_runtime.h>

typedef unsigned short u16;
typedef unsigned int u32;
typedef __bf16 bf16x8 __attribute__((ext_vector_type(8)));
typedef float f32x4 __attribute__((ext_vector_type(4)));

#define MFMA16(a, b, c) __builtin_amdgcn_mfma_f32_16x16x32_bf16((a), (b), (c), 0, 0, 0)

__device__ __forceinline__ u16 f2bf(float x) {
    union { float f; u32 u; } v; v.f = x;
    u32 r = v.u + 0x7fffu + ((v.u >> 16) & 1u);
    return (u16)(r >> 16);
}

typedef const __attribute__((address_space(1))) u32* gas1_t;
typedef __attribute__((address_space(3))) u32* las3_t;
__device__ __forceinline__ void g2lds16(const void* g, void* l) {
    __builtin_amdgcn_global_load_lds((gas1_t)g, (las3_t)l, 16, 0, 0);
}

// ---------------------------------------------------------------------------
// GEMM: C(M,N) = A(M,K)bf16 @ BT(N,K)bf16^T + bias, fused epilogues.
// MODE 0: += PE(t,d); write f32 + bf16  (in-proj)
// MODE 1: write bf16                     (qkv)
// MODE 2: += resid; write f32 (in-place residual add OK)   (o-proj / ff2)
// MODE 3: relu; write bf16               (ff1)
// m97 structure: 128x128 tile, BK=32, 4 waves each 64x64, global_load_lds.
// ---------------------------------------------------------------------------
template <int MODE>
__global__ __launch_bounds__(256) void gemm_bf16(
    const u16* __restrict__ A, const u16* __restrict__ BT,
    const float* __restrict__ bias, float* __restrict__ outF,
    u16* __restrict__ outB, const float* __restrict__ resid,
    int M, int N, int K)
{
    __shared__ u16 As[128 * 32];
    __shared__ u16 Bs[128 * 32];
    const int tid = threadIdx.x;
    const int w = tid >> 6, l = tid & 63;
    const int bm = blockIdx.y * 128, bn = blockIdx.x * 128;
    const int wr = (w >> 1) * 64, wc = (w & 1) * 64;
    const int larow = l >> 2, lacol = (l & 3) * 8;
    f32x4 acc[4][4] = {};

    for (int kt = 0; kt < K; kt += 32) {
        __syncthreads();
        #pragma unroll
        for (int q = 0; q < 2; ++q) {
            const int r0 = 16 * (w + 4 * q);
            g2lds16(&A[(size_t)(bm + r0 + larow) * K + kt + lacol], &As[r0 * 32]);
            g2lds16(&BT[(size_t)(bn + r0 + larow) * K + kt + lacol], &Bs[r0 * 32]);
        }
        __syncthreads();
        bf16x8 af[4], bfr[4];
        #pragma unroll
        for (int i = 0; i < 4; ++i)
            af[i] = *(const bf16x8*)&As[(wr + i * 16 + (l & 15)) * 32 + 8 * (l >> 4)];
        #pragma unroll
        for (int j = 0; j < 4; ++j)
            bfr[j] = *(const bf16x8*)&Bs[(wc + j * 16 + (l & 15)) * 32 + 8 * (l >> 4)];
        #pragma unroll
        for (int i = 0; i < 4; ++i)
            #pragma unroll
            for (int j = 0; j < 4; ++j)
                acc[i][j] = MFMA16(af[i], bfr[j], acc[i][j]);
    }

    const int r0 = bm + wr + (l >> 4) * 4;
    const int c0 = bn + wc + (l & 15);
    #pragma unroll
    for (int i = 0; i < 4; ++i) {
        #pragma unroll
        for (int j = 0; j < 4; ++j) {
            const int col = c0 + j * 16;
            const float bc = bias[col];
            #pragma unroll
            for (int r = 0; r < 4; ++r) {
                const int row = r0 + i * 16 + r;
                const size_t idx = (size_t)row * N + col;
                float val = acc[i][j][r] + bc;
                if constexpr (MODE == 0) {
                    const int t = row & 2047;
                    const int e = col & ~1;
                    const float fr = expf((float)e * -0.017988946039015984f); // -ln(1e4)/512
                    const float arg = (float)t * fr;
                    val += (col & 1) ? cosf(arg) : sinf(arg);
                    outF[idx] = val;
                    outB[idx] = f2bf(val);
                } else if constexpr (MODE == 1) {
                    outB[idx] = f2bf(val);
                } else if constexpr (MODE == 2) {
                    outF[idx] = val + resid[idx];
                } else {
                    outB[idx] = f2bf(fmaxf(val, 0.f));
                }
            }
        }
    }
}

// ---------------------------------------------------------------------------
// Flash attention. Block = (b, h, 64-row q-tile), 4 waves x 16 q-rows.
// Mask structure: row i (L = obs[b]):
//   i <= L : keys [lo, i], lo = (i>64 && i<L) ? i-64 : 0
//   i >  L : pad row, value irrelevant downstream (kept finite) -> key 0 only
// ---------------------------------------------------------------------------
__global__ __launch_bounds__(256) void attn_kernel(
    const u16* __restrict__ QKV, u16* __restrict__ CTX, const int* __restrict__ obs)
{
    __shared__ u16 Qs[64 * 64];
    __shared__ u16 Ks[64 * 64];
    __shared__ u16 Vt[64 * 64];
    __shared__ u16 Ps[4][16 * 64];
    const int b = blockIdx.z, h = blockIdx.y, i0 = blockIdx.x * 64;
    const int L = obs[b];
    const int tid = threadIdx.x, w = tid >> 6, l = tid & 63;
    const size_t tb = (size_t)b * 2048;
    {
        const int r = tid >> 3, c8 = (tid & 7) * 8;
        #pragma unroll
        for (int q = 0; q < 2; ++q) {
            const int row = r + 32 * q;
            *(uint4*)&Qs[row * 64 + c8] =
                *(const uint4*)&QKV[(tb + i0 + row) * 1536 + h * 64 + c8];
        }
    }
    __syncthreads();
    bf16x8 qa0, qa1;
    {
        const int row = 16 * w + (l & 15);
        qa0 = *(const bf16x8*)&Qs[row * 64 + 8 * (l >> 4)];
        qa1 = *(const bf16x8*)&Qs[row * 64 + 32 + 8 * (l >> 4)];
    }
    float m_r[4] = {-1e30f, -1e30f, -1e30f, -1e30f};
    float l_r[4] = {0.f, 0.f, 0.f, 0.f};
    f32x4 acc_o[4] = {};
    int hi_max = i0 + 63; if (hi_max > L) hi_max = L;
    if (i0 > L) hi_max = 0;  // whole tile is pad rows -> only key 0 needed
    const int lo_min = (i0 > 64 && (i0 + 63) < L) ? (i0 - 64) : 0;

    for (int j0 = lo_min & ~63; j0 <= hi_max; j0 += 64) {
        __syncthreads();
        {
            const int r = tid >> 3, c8 = (tid & 7) * 8;
            #pragma unroll
            for (int q = 0; q < 2; ++q) {
                const int row = r + 32 * q;
                *(uint4*)&Ks[row * 64 + c8] =
                    *(const uint4*)&QKV[(tb + j0 + row) * 1536 + 512 + h * 64 + c8];
                uint4 vv = *(const uint4*)&QKV[(tb + j0 + row) * 1536 + 1024 + h * 64 + c8];
                const u16* vs = (const u16*)&vv;
                #pragma unroll
                for (int e = 0; e < 8; ++e) Vt[(c8 + e) * 64 + row] = vs[e];
            }
        }
        __syncthreads();
        f32x4 s[4];
        #pragma unroll
        for (int f = 0; f < 4; ++f) {
            f32x4 z = {0.f, 0.f, 0.f, 0.f};
            bf16x8 kb0 = *(const bf16x8*)&Ks[(f * 16 + (l & 15)) * 64 + 8 * (l >> 4)];
            bf16x8 kb1 = *(const bf16x8*)&Ks[(f * 16 + (l & 15)) * 64 + 32 + 8 * (l >> 4)];
            z = MFMA16(qa0, kb0, z);
            z = MFMA16(qa1, kb1, z);
            s[f] = z;
        }
        float pm[4];
        #pragma unroll
        for (int r = 0; r < 4; ++r) {
            const int i_r = i0 + 16 * w + (l >> 4) * 4 + r;
            float mx = -__builtin_inff();
            #pragma unroll
            for (int f = 0; f < 4; ++f) {
                const int j = j0 + f * 16 + (l & 15);
                float sv = s[f][r] * 0.125f;
                const bool ok = (i_r > L) ? (j == 0)
                              : (j <= i_r && (i_r <= 64 || i_r >= L || j >= i_r - 64));
                sv = ok ? sv : -__builtin_inff();
                s[f][r] = sv;
                mx = fmaxf(mx, sv);
            }
            pm[r] = mx;
        }
        #pragma unroll
        for (int d = 1; d < 16; d <<= 1)
            #pragma unroll
            for (int r = 0; r < 4; ++r) pm[r] = fmaxf(pm[r], __shfl_xor(pm[r], d, 64));
        float sc[4];
        #pragma unroll
        for (int r = 0; r < 4; ++r) {
            const float mn = fmaxf(m_r[r], fmaxf(pm[r], -1e30f));
            sc[r] = __expf(m_r[r] - mn);
            m_r[r] = mn;
            l_r[r] *= sc[r];
        }
        #pragma unroll
        for (int f = 0; f < 4; ++f)
            #pragma unroll
            for (int r = 0; r < 4; ++r) acc_o[f][r] *= sc[r];
        float ps[4] = {0.f, 0.f, 0.f, 0.f};
        #pragma unroll
        for (int f = 0; f < 4; ++f)
            #pragma unroll
            for (int r = 0; r < 4; ++r) {
                const float p = __expf(s[f][r] - m_r[r]);  // exp(-inf)=0 for masked
                s[f][r] = p;
                ps[r] += p;
            }
        #pragma unroll
        for (int d = 1; d < 16; d <<= 1)
            #pragma unroll
            for (int r = 0; r < 4; ++r) ps[r] += __shfl_xor(ps[r], d, 64);
        #pragma unroll
        for (int r = 0; r < 4; ++r) l_r[r] += ps[r];
        // P (C-layout) -> LDS -> A-fragment layout
        #pragma unroll
        for (int f = 0; f < 4; ++f)
            #pragma unroll
            for (int r = 0; r < 4; ++r)
                Ps[w][((l >> 4) * 4 + r) * 64 + f * 16 + (l & 15)] = f2bf(s[f][r]);
        bf16x8 pa0 = *(const bf16x8*)&Ps[w][(l & 15) * 64 + 8 * (l >> 4)];
        bf16x8 pa1 = *(const bf16x8*)&Ps[w][(l & 15) * 64 + 32 + 8 * (l >> 4)];
        #pragma unroll
        for (int f = 0; f < 4; ++f) {
            bf16x8 vb0 = *(const bf16x8*)&Vt[(f * 16 + (l & 15)) * 64 + 8 * (l >> 4)];
            bf16x8 vb1 = *(const bf16x8*)&Vt[(f * 16 + (l & 15)) * 64 + 32 + 8 * (l >> 4)];
            acc_o[f] = MFMA16(pa0, vb0, acc_o[f]);
            acc_o[f] = MFMA16(pa1, vb1, acc_o[f]);
        }
    }
    #pragma unroll
    for (int r = 0; r < 4; ++r) {
        const float inv = 1.f / l_r[r];
        const int row = i0 + 16 * w + (l >> 4) * 4 + r;
        #pragma unroll
        for (int f = 0; f < 4; ++f)
            CTX[(tb + row) * 512 + h * 64 + f * 16 + (l & 15)] = f2bf(acc_o[f][r] * inv);
    }
}

// ---------------------------------------------------------------------------
// LayerNorm over D=512 (in-place on X); 1 wave/token, 4 tokens/block.
// ---------------------------------------------------------------------------
__global__ __launch_bounds__(256) void ln_kernel(
    const float* __restrict__ Y, const float* __restrict__ gw,
    const float* __restrict__ bw, float* __restrict__ X, u16* __restrict__ Xb)
{
    const int tok = blockIdx.x * 4 + (threadIdx.x >> 6);
    const int l = threadIdx.x & 63;
    const float* y = &Y[(size_t)tok * 512 + l * 8];
    f32x4 v0 = *(const f32x4*)y;
    f32x4 v1 = *(const f32x4*)(y + 4);
    float s = 0.f, sq = 0.f;
    #pragma unroll
    for (int e = 0; e < 4; ++e) {
        s += v0[e] + v1[e];
        sq += v0[e] * v0[e] + v1[e] * v1[e];
    }
    #pragma unroll
    for (int d = 1; d < 64; d <<= 1) {
        s += __shfl_xor(s, d, 64);
        sq += __shfl_xor(sq, d, 64);
    }
    const float mean = s * (1.f / 512.f);
    const float var = sq * (1.f / 512.f) - mean * mean;
    const float rstd = rsqrtf(var + 1e-5f);
    f32x4 o0, o1;
    union { u16 us[8]; uint4 u4; } pk;
    #pragma unroll
    for (int e = 0; e < 8; ++e) {
        const int d = l * 8 + e;
        const float xv = (e < 4) ? v0[e] : v1[e - 4];
        const float ov = (xv - mean) * rstd * gw[d] + bw[d];
        if (e < 4) o0[e] = ov; else o1[e - 4] = ov;
        pk.us[e] = f2bf(ov);
    }
    float* xo = &X[(size_t)tok * 512 + l * 8];
    *(f32x4*)xo = o0;
    *(f32x4*)(xo + 4) = o1;
    *(uint4*)&Xb[(size_t)tok * 512 + l * 8] = pk.u4;
}

__global__ void cast_bf16_kernel(const float* __restrict__ in, u16* __restrict__ out, int n) {
    const int i = (blockIdx.x * 256 + threadIdx.x) * 4;
    if (i + 3 < n) {
        f32x4 v = *(const f32x4*)&in[i];
        union { u16 us[4]; uint2 u2; } pk;
        #pragma unroll
        for (int e = 0; e < 4; ++e) pk.us[e] = f2bf(v[e]);
        *(uint2*)&out[i] = pk.u2;
    }
}

__global__ void transpose_cast(const float* __restrict__ W, u16* __restrict__ WT, int K, int N) {
    __shared__ float t[32][33];
    const int n0 = blockIdx.x * 32, k0 = blockIdx.y * 32;
    const int tx = threadIdx.x, ty = threadIdx.y;
    #pragma unroll
    for (int r = 0; r < 32; r += 8)
        t[ty + r][tx] = W[(size_t)(k0 + ty + r) * N + n0 + tx];
    __syncthreads();
    #pragma unroll
    for (int r = 0; r < 32; r += 8)
        WT[(size_t)(n0 + ty + r) * K + k0 + tx] = f2bf(t[tx][ty + r]);
}

__global__ void agg_partial(const float* __restrict__ X, float* __restrict__ part,
                            const int* __restrict__ obs) {
    const int b = blockIdx.y, c = blockIdx.x, d = threadIdx.x;
    const int L = obs[b];
    float s = 0.f;
    const int t0 = c * 128;
    int tend = t0 + 128;
    if (tend > L + 1) tend = L + 1;
    for (int t = t0; t < tend; ++t) s += X[((size_t)b * 2048 + t) * 512 + d];
    part[((size_t)b * 16 + c) * 512 + d] = s;
}

__global__ void agg_final(const float* __restrict__ part, float* __restrict__ out,
                          const int* __restrict__ obs) {
    const int b = blockIdx.x, d = threadIdx.x;
    float s = 0.f;
    #pragma unroll
    for (int c = 0; c < 16; ++c) s += part[((size_t)b * 16 + c) * 512 + d];
    out[b * 512 + d] = s / (float)(obs[b] + 1);
}

// ---------------------------------------------------------------------------
// Workspace budget (~141 MB):
//   U   32 MB  (traj-bf16 / QKV-chunk / FF-hidden-chunk, phases disjoint)
//   Xb  32 MB  (bf16 activations; attention ctx aliases it after QKV reads)
//   X   64 MB  (f32 residual stream, in-place add + in-place LN)
//   weights 7 MB (per-layer staged, reused), part 0.5 MB
// ---------------------------------------------------------------------------
extern "C" void kernel_launch(void* const* d_in, const int* in_sizes, int n_in,
                              void* d_out, int out_size, void* d_ws, size_t ws_size,
                              hipStream_t stream)
{
    const int M = 32768;     // B*T
    const int CH = 8192;     // rows per chunk (4 batches)
    const float* traj = (const float*)d_in[0];
    const int* obs = (const int*)d_in[1];
    const float* w_in = (const float*)d_in[2];
    const float* b_in = (const float*)d_in[3];

    char* base = (char*)d_ws;
    size_t off = 0;
    auto carve = [&](size_t bytes) -> void* {
        void* p = base + off;
        off += (bytes + 255) & ~(size_t)255;
        return p;
    };
    u16* U     = (u16*)carve((size_t)CH * 2048 * 2);    // 32 MB
    u16* Xb    = (u16*)carve((size_t)M * 512 * 2);      // 32 MB
    float* X   = (float*)carve((size_t)M * 512 * 4);    // 64 MB
    float* part = (float*)carve((size_t)16 * 16 * 512 * 4);
    u16* wTin  = (u16*)carve((size_t)512 * 512 * 2);
    u16* wqkv  = (u16*)carve((size_t)1536 * 512 * 2);
    u16* wo    = (u16*)carve((size_t)512 * 512 * 2);
    u16* wff1  = (u16*)carve((size_t)2048 * 512 * 2);
    u16* wff2  = (u16*)carve((size_t)512 * 2048 * 2);

    dim3 tb32(32, 8);
    transpose_cast<<<dim3(16, 16), tb32, 0, stream>>>(w_in, wTin, 512, 512);

    // input projection (chunked through U): X = traj @ w_in + b_in + PE
    for (int c = 0; c < 4; ++c) {
        cast_bf16_kernel<<<(CH * 512) / 1024, 256, 0, stream>>>(
            traj + (size_t)c * CH * 512, U, CH * 512);
        gemm_bf16<0><<<dim3(4, CH / 128), 256, 0, stream>>>(
            U, wTin, b_in, X + (size_t)c * CH * 512, Xb + (size_t)c * CH * 512,
            nullptr, CH, 512, 512);
    }

    for (int lyr = 0; lyr < 4; ++lyr) {
        const int bi = 4 + 12 * lyr;
        transpose_cast<<<dim3(48, 16), tb32, 0, stream>>>((const float*)d_in[bi + 0], wqkv, 512, 1536);
        transpose_cast<<<dim3(16, 16), tb32, 0, stream>>>((const float*)d_in[bi + 2], wo, 512, 512);
        transpose_cast<<<dim3(64, 16), tb32, 0, stream>>>((const float*)d_in[bi + 4], wff1, 512, 2048);
        transpose_cast<<<dim3(16, 64), tb32, 0, stream>>>((const float*)d_in[bi + 6], wff2, 2048, 512);
        const float* b_qkv = (const float*)d_in[bi + 1];
        const float* b_o   = (const float*)d_in[bi + 3];
        const float* b_ff1 = (const float*)d_in[bi + 5];
        const float* b_ff2 = (const float*)d_in[bi + 7];
        const float* ln1g  = (const float*)d_in[bi + 8];
        const float* ln1b  = (const float*)d_in[bi + 9];
        const float* ln2g  = (const float*)d_in[bi + 10];
        const float* ln2b  = (const float*)d_in[bi + 11];

        // QKV + attention, 4 batches at a time through U; ctx overwrites Xb.
        for (int c = 0; c < 4; ++c) {
            gemm_bf16<1><<<dim3(12, CH / 128), 256, 0, stream>>>(
                Xb + (size_t)c * CH * 512, wqkv, b_qkv, nullptr, U, nullptr,
                CH, 1536, 512);
            attn_kernel<<<dim3(32, 8, 4), 256, 0, stream>>>(
                U, Xb + (size_t)c * CH * 512, obs + c * 4);
        }
        gemm_bf16<2><<<dim3(4, M / 128), 256, 0, stream>>>(
            Xb, wo, b_o, X, nullptr, X, M, 512, 512);
        ln_kernel<<<M / 4, 256, 0, stream>>>(X, ln1g, ln1b, X, Xb);
        for (int c = 0; c < 4; ++c) {
            gemm_bf16<3><<<dim3(16, CH / 128), 256, 0, stream>>>(
                Xb + (size_t)c * CH * 512, wff1, b_ff1, nullptr, U, nullptr,
                CH, 2048, 512);
            gemm_bf16<2><<<dim3(4, CH / 128), 256, 0, stream>>>(
                U, wff2, b_ff2, X + (size_t)c * CH * 512, nullptr,
                X + (size_t)c * CH * 512, CH, 512, 2048);
        }
        ln_kernel<<<M / 4, 256, 0, stream>>>(X, ln2g, ln2b, X, Xb);
    }

    agg_partial<<<dim3(16, 16), 512, 0, stream>>>(X, part, obs);
    agg_final<<<16, 512, 0, stream>>>(part, (float*)d_out, obs);
}

// Round 3
// 2284.702 us; speedup vs baseline: 1.7208x; 1.7208x over previous
//
#include <hip/hip_runtime.h>

typedef unsigned short u16;
typedef unsigned int u32;
typedef __bf16 bf16x8 __attribute__((ext_vector_type(8)));
typedef float f32x4 __attribute__((ext_vector_type(4)));

#define MFMA16(a, b, c) __builtin_amdgcn_mfma_f32_16x16x32_bf16((a), (b), (c), 0, 0, 0)

__device__ __forceinline__ u16 f2bf(float x) {
    union { float f; u32 u; } v; v.f = x;
    u32 r = v.u + 0x7fffu + ((v.u >> 16) & 1u);
    return (u16)(r >> 16);
}
__device__ __forceinline__ float bf2f(u16 x) {
    union { u32 u; float f; } v; v.u = ((u32)x) << 16; return v.f;
}

typedef const __attribute__((address_space(1))) u32* gas1_t;
typedef __attribute__((address_space(3))) u32* las3_t;
__device__ __forceinline__ void g2lds16(const void* g, void* l) {
    __builtin_amdgcn_global_load_lds((gas1_t)g, (las3_t)l, 16, 0, 0);
}

// ---------------------------------------------------------------------------
// GEMM: C(M,N) = A(M,K)bf16 @ BT(N,K)bf16^T + bias, fused epilogues.
// MODE 0: += PE(t,d); write f32 + bf16  (in-proj)
// MODE 1: write bf16                     (qkv)
// MODE 2: += resid; write f32 (in-place OK)   (o-proj / ff2)
// MODE 3: relu; write bf16               (ff1)
// m97 structure + bijective XCD swizzle (row-contiguous chunks per XCD).
// ---------------------------------------------------------------------------
template <int MODE>
__global__ __launch_bounds__(256) void gemm_bf16(
    const u16* __restrict__ A, const u16* __restrict__ BT,
    const float* __restrict__ bias, float* __restrict__ outF,
    u16* __restrict__ outB, const float* __restrict__ resid,
    int M, int N, int K)
{
    __shared__ u16 As[128 * 32];
    __shared__ u16 Bs[128 * 32];
    const int tid = threadIdx.x;
    const int w = tid >> 6, l = tid & 63;
    // XCD-aware bijective swizzle (m204): contiguous wgid chunk per XCD.
    const int gx = gridDim.x;
    const int nwg = gx * gridDim.y;
    const int orig = blockIdx.y * gx + blockIdx.x;
    const int q8 = nwg >> 3, r8 = nwg & 7;
    const int xcd = orig & 7, loc = orig >> 3;
    const int wgid = (xcd < r8 ? xcd * (q8 + 1) : r8 * (q8 + 1) + (xcd - r8) * q8) + loc;
    const int bm = (wgid / gx) * 128, bn = (wgid % gx) * 128;
    const int wr = (w >> 1) * 64, wc = (w & 1) * 64;
    const int larow = l >> 2, lacol = (l & 3) * 8;
    f32x4 acc[4][4] = {};

    for (int kt = 0; kt < K; kt += 32) {
        __syncthreads();
        #pragma unroll
        for (int q = 0; q < 2; ++q) {
            const int r0 = 16 * (w + 4 * q);
            g2lds16(&A[(size_t)(bm + r0 + larow) * K + kt + lacol], &As[r0 * 32]);
            g2lds16(&BT[(size_t)(bn + r0 + larow) * K + kt + lacol], &Bs[r0 * 32]);
        }
        __syncthreads();
        bf16x8 af[4], bfr[4];
        #pragma unroll
        for (int i = 0; i < 4; ++i)
            af[i] = *(const bf16x8*)&As[(wr + i * 16 + (l & 15)) * 32 + 8 * (l >> 4)];
        #pragma unroll
        for (int j = 0; j < 4; ++j)
            bfr[j] = *(const bf16x8*)&Bs[(wc + j * 16 + (l & 15)) * 32 + 8 * (l >> 4)];
        #pragma unroll
        for (int i = 0; i < 4; ++i)
            #pragma unroll
            for (int j = 0; j < 4; ++j)
                acc[i][j] = MFMA16(af[i], bfr[j], acc[i][j]);
    }

    const int r0 = bm + wr + (l >> 4) * 4;
    const int c0 = bn + wc + (l & 15);
    #pragma unroll
    for (int i = 0; i < 4; ++i) {
        #pragma unroll
        for (int j = 0; j < 4; ++j) {
            const int col = c0 + j * 16;
            const float bc = bias[col];
            #pragma unroll
            for (int r = 0; r < 4; ++r) {
                const int row = r0 + i * 16 + r;
                const size_t idx = (size_t)row * N + col;
                float val = acc[i][j][r] + bc;
                if constexpr (MODE == 0) {
                    const int t = row & 2047;
                    const int e = col & ~1;
                    const float fr = expf((float)e * -0.017988946039015984f); // -ln(1e4)/512
                    const float arg = (float)t * fr;
                    val += (col & 1) ? cosf(arg) : sinf(arg);
                    outF[idx] = val;
                    outB[idx] = f2bf(val);
                } else if constexpr (MODE == 1) {
                    outB[idx] = f2bf(val);
                } else if constexpr (MODE == 2) {
                    outF[idx] = val + resid[idx];
                } else {
                    outB[idx] = f2bf(fmaxf(val, 0.f));
                }
            }
        }
    }
}

// ---------------------------------------------------------------------------
// Flash attention, two phases in one dispatch.
// Phase A (blockIdx.x < 32): 64-row q-tile, banded keys [klo, khi], <=2 k-tiles.
//   klo = (i0>=128) ? i0-64 : 0 covers every live row except row L.
//   Rows i> L are pad (any finite value); row i==L is NOT stored (phase B owns it).
// Phase B (blockIdx.x == 32): row L full causal attention over [0, L],
//   4 waves split the key range, online-softmax merge in LDS.
// ---------------------------------------------------------------------------
__global__ __launch_bounds__(256) void attn_kernel(
    const u16* __restrict__ QKV, u16* __restrict__ CTX, const int* __restrict__ obs)
{
    __shared__ u16 Qs[64 * 64];
    __shared__ u16 Ks[64 * 64];
    __shared__ u16 Vt[64 * 64];
    __shared__ u16 Ps[4][16 * 64];
    const int b = blockIdx.z, h = blockIdx.y;
    const int L = obs[b];
    const int tid = threadIdx.x, w = tid >> 6, l = tid & 63;
    const size_t tb = (size_t)b * 2048;

    if (blockIdx.x == 32) {
        // ---- Phase B: row L, keys [0, L] ----
        float* pP = (float*)Ks;        // [4][64] per-wave P
        float* oW = (float*)Vt;        // [4][64] per-wave O
        float* mW = (float*)Ps;        // [4] max, [4] sum at offset 8
        u16 q16[64];
        #pragma unroll
        for (int dd = 0; dd < 8; ++dd)
            *(uint4*)&q16[dd * 8] = *(const uint4*)&QKV[(tb + L) * 1536 + h * 64 + dd * 8];
        float m = -3.0e38f, lsum = 0.f, oacc = 0.f;
        for (int j0 = w * 64; j0 <= L; j0 += 256) {
            const int j = j0 + l;
            const bool val = (j <= L);
            float s = -3.0e38f;
            if (val) {
                s = 0.f;
                const u16* kp = &QKV[(tb + j) * 1536 + 512 + h * 64];
                #pragma unroll
                for (int dd = 0; dd < 8; ++dd) {
                    uint4 kk = *(const uint4*)&kp[dd * 8];
                    const u16* ke = (const u16*)&kk;
                    #pragma unroll
                    for (int e = 0; e < 8; ++e)
                        s += bf2f(q16[dd * 8 + e]) * bf2f(ke[e]);
                }
                s *= 0.125f;
            }
            float mx = s;
            #pragma unroll
            for (int d = 1; d < 64; d <<= 1) mx = fmaxf(mx, __shfl_xor(mx, d, 64));
            const float mn = fmaxf(m, mx);
            const float sc = __expf(m - mn);
            m = mn;
            const float p = val ? __expf(s - mn) : 0.f;
            float ps = p;
            #pragma unroll
            for (int d = 1; d < 64; d <<= 1) ps += __shfl_xor(ps, d, 64);
            lsum = lsum * sc + ps;
            oacc *= sc;
            pP[w * 64 + l] = p;
            __builtin_amdgcn_wave_barrier();
            #pragma unroll 4
            for (int jj = 0; jj < 64; ++jj) {
                const int rr = (j0 + jj <= L) ? (j0 + jj) : L;
                oacc += pP[w * 64 + jj] * bf2f(QKV[(tb + rr) * 1536 + 1024 + h * 64 + l]);
            }
            __builtin_amdgcn_wave_barrier();
        }
        oW[w * 64 + l] = oacc;
        if (l == 0) { mW[w] = m; mW[8 + w] = lsum; }
        __syncthreads();
        if (w == 0) {
            float mstar = fmaxf(fmaxf(mW[0], mW[1]), fmaxf(mW[2], mW[3]));
            float ot = 0.f, lt = 0.f;
            #pragma unroll
            for (int ww = 0; ww < 4; ++ww) {
                const float sc = __expf(mW[ww] - mstar);
                ot += sc * oW[ww * 64 + l];
                lt += sc * mW[8 + ww];
            }
            CTX[(tb + L) * 512 + h * 64 + l] = f2bf(ot / lt);
        }
        return;
    }

    // ---- Phase A ----
    const int i0 = blockIdx.x * 64;
    {
        const int r = tid >> 3, c8 = (tid & 7) * 8;
        #pragma unroll
        for (int q = 0; q < 2; ++q) {
            const int row = r + 32 * q;
            *(uint4*)&Qs[row * 64 + c8] =
                *(const uint4*)&QKV[(tb + i0 + row) * 1536 + h * 64 + c8];
        }
    }
    __syncthreads();
    bf16x8 qa0, qa1;
    {
        const int row = 16 * w + (l & 15);
        qa0 = *(const bf16x8*)&Qs[row * 64 + 8 * (l >> 4)];
        qa1 = *(const bf16x8*)&Qs[row * 64 + 32 + 8 * (l >> 4)];
    }
    float m_r[4] = {-1e30f, -1e30f, -1e30f, -1e30f};
    float l_r[4] = {0.f, 0.f, 0.f, 0.f};
    f32x4 acc_o[4] = {};
    const int klo = (i0 >= 128) ? (i0 - 64) : 0;
    int khi = (L < klo) ? klo : min(i0 + 63, L);

    for (int j0 = klo; j0 <= khi; j0 += 64) {
        __syncthreads();
        {
            const int r = tid >> 3, c8 = (tid & 7) * 8;
            #pragma unroll
            for (int q = 0; q < 2; ++q) {
                const int row = r + 32 * q;
                *(uint4*)&Ks[row * 64 + c8] =
                    *(const uint4*)&QKV[(tb + j0 + row) * 1536 + 512 + h * 64 + c8];
                uint4 vv = *(const uint4*)&QKV[(tb + j0 + row) * 1536 + 1024 + h * 64 + c8];
                const u16* vs = (const u16*)&vv;
                #pragma unroll
                for (int e = 0; e < 8; ++e) Vt[(c8 + e) * 64 + row] = vs[e];
            }
        }
        __syncthreads();
        f32x4 s[4];
        #pragma unroll
        for (int f = 0; f < 4; ++f) {
            f32x4 z = {0.f, 0.f, 0.f, 0.f};
            bf16x8 kb0 = *(const bf16x8*)&Ks[(f * 16 + (l & 15)) * 64 + 8 * (l >> 4)];
            bf16x8 kb1 = *(const bf16x8*)&Ks[(f * 16 + (l & 15)) * 64 + 32 + 8 * (l >> 4)];
            z = MFMA16(qa0, kb0, z);
            z = MFMA16(qa1, kb1, z);
            s[f] = z;
        }
        float pm[4];
        #pragma unroll
        for (int r = 0; r < 4; ++r) {
            const int i_r = i0 + 16 * w + (l >> 4) * 4 + r;
            float mx = -__builtin_inff();
            #pragma unroll
            for (int f = 0; f < 4; ++f) {
                const int j = j0 + f * 16 + (l & 15);
                float sv = s[f][r] * 0.125f;
                const bool ok = (i_r >= L) ? (j == klo)
                              : (j <= i_r && (i_r <= 64 || j >= i_r - 64));
                sv = ok ? sv : -__builtin_inff();
                s[f][r] = sv;
                mx = fmaxf(mx, sv);
            }
            pm[r] = mx;
        }
        #pragma unroll
        for (int d = 1; d < 16; d <<= 1)
            #pragma unroll
            for (int r = 0; r < 4; ++r) pm[r] = fmaxf(pm[r], __shfl_xor(pm[r], d, 64));
        float sc[4];
        #pragma unroll
        for (int r = 0; r < 4; ++r) {
            const float mn = fmaxf(m_r[r], fmaxf(pm[r], -1e30f));
            sc[r] = __expf(m_r[r] - mn);
            m_r[r] = mn;
            l_r[r] *= sc[r];
        }
        #pragma unroll
        for (int f = 0; f < 4; ++f)
            #pragma unroll
            for (int r = 0; r < 4; ++r) acc_o[f][r] *= sc[r];
        float ps[4] = {0.f, 0.f, 0.f, 0.f};
        #pragma unroll
        for (int f = 0; f < 4; ++f)
            #pragma unroll
            for (int r = 0; r < 4; ++r) {
                const float p = __expf(s[f][r] - m_r[r]);
                s[f][r] = p;
                ps[r] += p;
            }
        #pragma unroll
        for (int d = 1; d < 16; d <<= 1)
            #pragma unroll
            for (int r = 0; r < 4; ++r) ps[r] += __shfl_xor(ps[r], d, 64);
        #pragma unroll
        for (int r = 0; r < 4; ++r) l_r[r] += ps[r];
        #pragma unroll
        for (int f = 0; f < 4; ++f)
            #pragma unroll
            for (int r = 0; r < 4; ++r)
                Ps[w][((l >> 4) * 4 + r) * 64 + f * 16 + (l & 15)] = f2bf(s[f][r]);
        bf16x8 pa0 = *(const bf16x8*)&Ps[w][(l & 15) * 64 + 8 * (l >> 4)];
        bf16x8 pa1 = *(const bf16x8*)&Ps[w][(l & 15) * 64 + 32 + 8 * (l >> 4)];
        #pragma unroll
        for (int f = 0; f < 4; ++f) {
            bf16x8 vb0 = *(const bf16x8*)&Vt[(f * 16 + (l & 15)) * 64 + 8 * (l >> 4)];
            bf16x8 vb1 = *(const bf16x8*)&Vt[(f * 16 + (l & 15)) * 64 + 32 + 8 * (l >> 4)];
            acc_o[f] = MFMA16(pa0, vb0, acc_o[f]);
            acc_o[f] = MFMA16(pa1, vb1, acc_o[f]);
        }
    }
    #pragma unroll
    for (int r = 0; r < 4; ++r) {
        const float inv = 1.f / l_r[r];
        const int row = i0 + 16 * w + (l >> 4) * 4 + r;
        if (row != L) {
            #pragma unroll
            for (int f = 0; f < 4; ++f)
                CTX[(tb + row) * 512 + h * 64 + f * 16 + (l & 15)] = f2bf(acc_o[f][r] * inv);
        }
    }
}

// ---------------------------------------------------------------------------
__global__ __launch_bounds__(256) void ln_kernel(
    const float* __restrict__ Y, const float* __restrict__ gw,
    const float* __restrict__ bw, float* __restrict__ X, u16* __restrict__ Xb)
{
    const int tok = blockIdx.x * 4 + (threadIdx.x >> 6);
    const int l = threadIdx.x & 63;
    const float* y = &Y[(size_t)tok * 512 + l * 8];
    f32x4 v0 = *(const f32x4*)y;
    f32x4 v1 = *(const f32x4*)(y + 4);
    float s = 0.f, sq = 0.f;
    #pragma unroll
    for (int e = 0; e < 4; ++e) {
        s += v0[e] + v1[e];
        sq += v0[e] * v0[e] + v1[e] * v1[e];
    }
    #pragma unroll
    for (int d = 1; d < 64; d <<= 1) {
        s += __shfl_xor(s, d, 64);
        sq += __shfl_xor(sq, d, 64);
    }
    const float mean = s * (1.f / 512.f);
    const float var = sq * (1.f / 512.f) - mean * mean;
    const float rstd = rsqrtf(var + 1e-5f);
    f32x4 o0, o1;
    union { u16 us[8]; uint4 u4; } pk;
    #pragma unroll
    for (int e = 0; e < 8; ++e) {
        const int d = l * 8 + e;
        const float xv = (e < 4) ? v0[e] : v1[e - 4];
        const float ov = (xv - mean) * rstd * gw[d] + bw[d];
        if (e < 4) o0[e] = ov; else o1[e - 4] = ov;
        pk.us[e] = f2bf(ov);
    }
    float* xo = &X[(size_t)tok * 512 + l * 8];
    *(f32x4*)xo = o0;
    *(f32x4*)(xo + 4) = o1;
    *(uint4*)&Xb[(size_t)tok * 512 + l * 8] = pk.u4;
}

__global__ void cast_bf16_kernel(const float* __restrict__ in, u16* __restrict__ out, int n) {
    const int i = (blockIdx.x * 256 + threadIdx.x) * 4;
    if (i + 3 < n) {
        f32x4 v = *(const f32x4*)&in[i];
        union { u16 us[4]; uint2 u2; } pk;
        #pragma unroll
        for (int e = 0; e < 4; ++e) pk.us[e] = f2bf(v[e]);
        *(uint2*)&out[i] = pk.u2;
    }
}

__global__ void transpose_cast(const float* __restrict__ W, u16* __restrict__ WT, int K, int N) {
    __shared__ float t[32][33];
    const int n0 = blockIdx.x * 32, k0 = blockIdx.y * 32;
    const int tx = threadIdx.x, ty = threadIdx.y;
    #pragma unroll
    for (int r = 0; r < 32; r += 8)
        t[ty + r][tx] = W[(size_t)(k0 + ty + r) * N + n0 + tx];
    __syncthreads();
    #pragma unroll
    for (int r = 0; r < 32; r += 8)
        WT[(size_t)(n0 + ty + r) * K + k0 + tx] = f2bf(t[tx][ty + r]);
}

__global__ void agg_partial(const float* __restrict__ X, float* __restrict__ part,
                            const int* __restrict__ obs) {
    const int b = blockIdx.y, c = blockIdx.x, d = threadIdx.x;
    const int L = obs[b];
    float s = 0.f;
    const int t0 = c * 128;
    int tend = t0 + 128;
    if (tend > L + 1) tend = L + 1;
    for (int t = t0; t < tend; ++t) s += X[((size_t)b * 2048 + t) * 512 + d];
    part[((size_t)b * 16 + c) * 512 + d] = s;
}

__global__ void agg_final(const float* __restrict__ part, float* __restrict__ out,
                          const int* __restrict__ obs) {
    const int b = blockIdx.x, d = threadIdx.x;
    float s = 0.f;
    #pragma unroll
    for (int c = 0; c < 16; ++c) s += part[((size_t)b * 16 + c) * 512 + d];
    out[b * 512 + d] = s / (float)(obs[b] + 1);
}

// ---------------------------------------------------------------------------
extern "C" void kernel_launch(void* const* d_in, const int* in_sizes, int n_in,
                              void* d_out, int out_size, void* d_ws, size_t ws_size,
                              hipStream_t stream)
{
    const int M = 32768;     // B*T
    // If workspace is large enough, run QKV/FF un-chunked (fewer dispatches).
    const int nch = (ws_size >= (size_t)215 * 1024 * 1024) ? 1 : 4;
    const int CH = M / nch;          // rows per chunk
    const int BPC = 16 / nch;        // batches per chunk
    const float* traj = (const float*)d_in[0];
    const int* obs = (const int*)d_in[1];
    const float* w_in = (const float*)d_in[2];
    const float* b_in = (const float*)d_in[3];

    char* base = (char*)d_ws;
    size_t off = 0;
    auto carve = [&](size_t bytes) -> void* {
        void* p = base + off;
        off += (bytes + 255) & ~(size_t)255;
        return p;
    };
    u16* U     = (u16*)carve((size_t)CH * 2048 * 2);
    u16* Xb    = (u16*)carve((size_t)M * 512 * 2);
    float* X   = (float*)carve((size_t)M * 512 * 4);
    float* part = (float*)carve((size_t)16 * 16 * 512 * 4);
    u16* wTin  = (u16*)carve((size_t)512 * 512 * 2);
    u16* wqkv  = (u16*)carve((size_t)1536 * 512 * 2);
    u16* wo    = (u16*)carve((size_t)512 * 512 * 2);
    u16* wff1  = (u16*)carve((size_t)2048 * 512 * 2);
    u16* wff2  = (u16*)carve((size_t)512 * 2048 * 2);

    dim3 tb32(32, 8);
    transpose_cast<<<dim3(16, 16), tb32, 0, stream>>>(w_in, wTin, 512, 512);

    for (int c = 0; c < nch; ++c) {
        cast_bf16_kernel<<<(CH * 512) / 1024, 256, 0, stream>>>(
            traj + (size_t)c * CH * 512, U, CH * 512);
        gemm_bf16<0><<<dim3(4, CH / 128), 256, 0, stream>>>(
            U, wTin, b_in, X + (size_t)c * CH * 512, Xb + (size_t)c * CH * 512,
            nullptr, CH, 512, 512);
    }

    for (int lyr = 0; lyr < 4; ++lyr) {
        const int bi = 4 + 12 * lyr;
        transpose_cast<<<dim3(48, 16), tb32, 0, stream>>>((const float*)d_in[bi + 0], wqkv, 512, 1536);
        transpose_cast<<<dim3(16, 16), tb32, 0, stream>>>((const float*)d_in[bi + 2], wo, 512, 512);
        transpose_cast<<<dim3(64, 16), tb32, 0, stream>>>((const float*)d_in[bi + 4], wff1, 512, 2048);
        transpose_cast<<<dim3(16, 64), tb32, 0, stream>>>((const float*)d_in[bi + 6], wff2, 2048, 512);
        const float* b_qkv = (const float*)d_in[bi + 1];
        const float* b_o   = (const float*)d_in[bi + 3];
        const float* b_ff1 = (const float*)d_in[bi + 5];
        const float* b_ff2 = (const float*)d_in[bi + 7];
        const float* ln1g  = (const float*)d_in[bi + 8];
        const float* ln1b  = (const float*)d_in[bi + 9];
        const float* ln2g  = (const float*)d_in[bi + 10];
        const float* ln2b  = (const float*)d_in[bi + 11];

        for (int c = 0; c < nch; ++c) {
            gemm_bf16<1><<<dim3(12, CH / 128), 256, 0, stream>>>(
                Xb + (size_t)c * CH * 512, wqkv, b_qkv, nullptr, U, nullptr,
                CH, 1536, 512);
            attn_kernel<<<dim3(33, 8, BPC), 256, 0, stream>>>(
                U, Xb + (size_t)c * CH * 512, obs + c * BPC);
        }
        gemm_bf16<2><<<dim3(4, M / 128), 256, 0, stream>>>(
            Xb, wo, b_o, X, nullptr, X, M, 512, 512);
        ln_kernel<<<M / 4, 256, 0, stream>>>(X, ln1g, ln1b, X, Xb);
        for (int c = 0; c < nch; ++c) {
            gemm_bf16<3><<<dim3(16, CH / 128), 256, 0, stream>>>(
                Xb + (size_t)c * CH * 512, wff1, b_ff1, nullptr, U, nullptr,
                CH, 2048, 512);
            gemm_bf16<2><<<dim3(4, CH / 128), 256, 0, stream>>>(
                U, wff2, b_ff2, X + (size_t)c * CH * 512, nullptr,
                X + (size_t)c * CH * 512, CH, 512, 2048);
        }
        ln_kernel<<<M / 4, 256, 0, stream>>>(X, ln2g, ln2b, X, Xb);
    }

    agg_partial<<<dim3(16, 16), 512, 0, stream>>>(X, part, obs);
    agg_final<<<16, 512, 0, stream>>>(part, (float*)d_out, obs);
}

// Round 4
// 2005.378 us; speedup vs baseline: 1.9605x; 1.1393x over previous
//
#include <hip/hip_runtime.h>

typedef unsigned short u16;
typedef unsigned int u32;
typedef __bf16 bf16x8 __attribute__((ext_vector_type(8)));
typedef float f32x4 __attribute__((ext_vector_type(4)));

#define MFMA16(a, b, c) __builtin_amdgcn_mfma_f32_16x16x32_bf16((a), (b), (c), 0, 0, 0)

__device__ __forceinline__ u16 f2bf(float x) {
    union { float f; u32 u; } v; v.f = x;
    u32 r = v.u + 0x7fffu + ((v.u >> 16) & 1u);
    return (u16)(r >> 16);
}
__device__ __forceinline__ float bf2f(u16 x) {
    union { u32 u; float f; } v; v.u = ((u32)x) << 16; return v.f;
}

typedef const __attribute__((address_space(1))) u32* gas1_t;
typedef __attribute__((address_space(3))) u32* las3_t;
__device__ __forceinline__ void g2lds16(const void* g, void* l) {
    __builtin_amdgcn_global_load_lds((gas1_t)g, (las3_t)l, 16, 0, 0);
}

// ---------------------------------------------------------------------------
// GEMM: C(M,N) = A(M,K)bf16 @ BT(N,K)bf16^T + bias, fused epilogues.
// MODE 0: += PE(t,d); write f32 + bf16  (in-proj)
// MODE 1: write bf16                     (qkv)
// MODE 2: += resid; write f32 (in-place OK)   (o-proj / ff2)
// MODE 3: relu; write bf16               (ff1)
// m97 structure + bijective XCD swizzle + dead-tile skip (rows > obs[b] are
// pad rows whose values never influence kept outputs; leaving them stale is
// safe because all stale data is finite and always masked to exactly 0).
// ---------------------------------------------------------------------------
template <int MODE>
__global__ __launch_bounds__(256) void gemm_bf16(
    const u16* __restrict__ A, const u16* __restrict__ BT,
    const float* __restrict__ bias, float* __restrict__ outF,
    u16* __restrict__ outB, const float* __restrict__ resid,
    const int* __restrict__ obs,
    int M, int N, int K)
{
    __shared__ u16 As[128 * 32];
    __shared__ u16 Bs[128 * 32];
    const int tid = threadIdx.x;
    const int w = tid >> 6, l = tid & 63;
    // XCD-aware bijective swizzle (m204): contiguous wgid chunk per XCD.
    const int gx = gridDim.x;
    const int nwg = gx * gridDim.y;
    const int orig = blockIdx.y * gx + blockIdx.x;
    const int q8 = nwg >> 3, r8 = nwg & 7;
    const int xcd = orig & 7, loc = orig >> 3;
    const int wgid = (xcd < r8 ? xcd * (q8 + 1) : r8 * (q8 + 1) + (xcd - r8) * q8) + loc;
    const int bm = (wgid / gx) * 128, bn = (wgid % gx) * 128;
    // dead-tile skip: tile entirely above obs[batch] -> pad rows only.
    if ((bm & 2047) > obs[bm >> 11]) return;
    const int wr = (w >> 1) * 64, wc = (w & 1) * 64;
    const int larow = l >> 2, lacol = (l & 3) * 8;
    f32x4 acc[4][4] = {};

    for (int kt = 0; kt < K; kt += 32) {
        __syncthreads();
        #pragma unroll
        for (int q = 0; q < 2; ++q) {
            const int r0 = 16 * (w + 4 * q);
            g2lds16(&A[(size_t)(bm + r0 + larow) * K + kt + lacol], &As[r0 * 32]);
            g2lds16(&BT[(size_t)(bn + r0 + larow) * K + kt + lacol], &Bs[r0 * 32]);
        }
        __syncthreads();
        bf16x8 af[4], bfr[4];
        #pragma unroll
        for (int i = 0; i < 4; ++i)
            af[i] = *(const bf16x8*)&As[(wr + i * 16 + (l & 15)) * 32 + 8 * (l >> 4)];
        #pragma unroll
        for (int j = 0; j < 4; ++j)
            bfr[j] = *(const bf16x8*)&Bs[(wc + j * 16 + (l & 15)) * 32 + 8 * (l >> 4)];
        #pragma unroll
        for (int i = 0; i < 4; ++i)
            #pragma unroll
            for (int j = 0; j < 4; ++j)
                acc[i][j] = MFMA16(af[i], bfr[j], acc[i][j]);
    }

    const int r0 = bm + wr + (l >> 4) * 4;
    const int c0 = bn + wc + (l & 15);
    #pragma unroll
    for (int i = 0; i < 4; ++i) {
        #pragma unroll
        for (int j = 0; j < 4; ++j) {
            const int col = c0 + j * 16;
            const float bc = bias[col];
            #pragma unroll
            for (int r = 0; r < 4; ++r) {
                const int row = r0 + i * 16 + r;
                const size_t idx = (size_t)row * N + col;
                float val = acc[i][j][r] + bc;
                if constexpr (MODE == 0) {
                    const int t = row & 2047;
                    const int e = col & ~1;
                    const float fr = expf((float)e * -0.017988946039015984f); // -ln(1e4)/512
                    const float arg = (float)t * fr;
                    val += (col & 1) ? cosf(arg) : sinf(arg);
                    outF[idx] = val;
                    outB[idx] = f2bf(val);
                } else if constexpr (MODE == 1) {
                    outB[idx] = f2bf(val);
                } else if constexpr (MODE == 2) {
                    outF[idx] = val + resid[idx];
                } else {
                    outB[idx] = f2bf(fmaxf(val, 0.f));
                }
            }
        }
    }
}

// ---------------------------------------------------------------------------
// Flash attention, two phases in one dispatch.
// Phase A (blockIdx.x < 32): 64-row q-tile, banded keys [klo, khi], <=2 k-tiles.
//   klo = (i0>=128) ? i0-64 : 0 covers every live row except row L.
//   Tiles fully above L return immediately (pad rows stay stale, finite).
//   Row i==L is NOT stored (phase B owns it).
// Phase B (blockIdx.x == 32): row L full causal attention over [0, L],
//   4 waves split the key range, online-softmax merge in LDS.
// ---------------------------------------------------------------------------
__global__ __launch_bounds__(256) void attn_kernel(
    const u16* __restrict__ QKV, u16* __restrict__ CTX, const int* __restrict__ obs)
{
    __shared__ u16 Qs[64 * 64];
    __shared__ u16 Ks[64 * 64];
    __shared__ u16 Vt[64 * 64];
    __shared__ u16 Ps[4][16 * 64];
    const int b = blockIdx.z, h = blockIdx.y;
    const int L = obs[b];
    const int tid = threadIdx.x, w = tid >> 6, l = tid & 63;
    const size_t tb = (size_t)b * 2048;

    if (blockIdx.x != 32 && (int)blockIdx.x * 64 > L) return;  // dead q-tile

    if (blockIdx.x == 32) {
        // ---- Phase B: row L, keys [0, L] ----
        float* pP = (float*)Ks;        // [4][64] per-wave P
        float* oW = (float*)Vt;        // [4][64] per-wave O
        float* mW = (float*)Ps;        // [4] max, [4] sum at offset 8
        u16 q16[64];
        #pragma unroll
        for (int dd = 0; dd < 8; ++dd)
            *(uint4*)&q16[dd * 8] = *(const uint4*)&QKV[(tb + L) * 1536 + h * 64 + dd * 8];
        float m = -3.0e38f, lsum = 0.f, oacc = 0.f;
        for (int j0 = w * 64; j0 <= L; j0 += 256) {
            const int j = j0 + l;
            const bool val = (j <= L);
            float s = -3.0e38f;
            if (val) {
                s = 0.f;
                const u16* kp = &QKV[(tb + j) * 1536 + 512 + h * 64];
                #pragma unroll
                for (int dd = 0; dd < 8; ++dd) {
                    uint4 kk = *(const uint4*)&kp[dd * 8];
                    const u16* ke = (const u16*)&kk;
                    #pragma unroll
                    for (int e = 0; e < 8; ++e)
                        s += bf2f(q16[dd * 8 + e]) * bf2f(ke[e]);
                }
                s *= 0.125f;
            }
            float mx = s;
            #pragma unroll
            for (int d = 1; d < 64; d <<= 1) mx = fmaxf(mx, __shfl_xor(mx, d, 64));
            const float mn = fmaxf(m, mx);
            const float sc = __expf(m - mn);
            m = mn;
            const float p = val ? __expf(s - mn) : 0.f;
            float ps = p;
            #pragma unroll
            for (int d = 1; d < 64; d <<= 1) ps += __shfl_xor(ps, d, 64);
            lsum = lsum * sc + ps;
            oacc *= sc;
            pP[w * 64 + l] = p;
            __builtin_amdgcn_wave_barrier();
            #pragma unroll 4
            for (int jj = 0; jj < 64; ++jj) {
                const int rr = (j0 + jj <= L) ? (j0 + jj) : L;
                oacc += pP[w * 64 + jj] * bf2f(QKV[(tb + rr) * 1536 + 1024 + h * 64 + l]);
            }
            __builtin_amdgcn_wave_barrier();
        }
        oW[w * 64 + l] = oacc;
        if (l == 0) { mW[w] = m; mW[8 + w] = lsum; }
        __syncthreads();
        if (w == 0) {
            float mstar = fmaxf(fmaxf(mW[0], mW[1]), fmaxf(mW[2], mW[3]));
            float ot = 0.f, lt = 0.f;
            #pragma unroll
            for (int ww = 0; ww < 4; ++ww) {
                const float sc = __expf(mW[ww] - mstar);
                ot += sc * oW[ww * 64 + l];
                lt += sc * mW[8 + ww];
            }
            CTX[(tb + L) * 512 + h * 64 + l] = f2bf(ot / lt);
        }
        return;
    }

    // ---- Phase A ----
    const int i0 = blockIdx.x * 64;
    {
        const int r = tid >> 3, c8 = (tid & 7) * 8;
        #pragma unroll
        for (int q = 0; q < 2; ++q) {
            const int row = r + 32 * q;
            *(uint4*)&Qs[row * 64 + c8] =
                *(const uint4*)&QKV[(tb + i0 + row) * 1536 + h * 64 + c8];
        }
    }
    __syncthreads();
    bf16x8 qa0, qa1;
    {
        const int row = 16 * w + (l & 15);
        qa0 = *(const bf16x8*)&Qs[row * 64 + 8 * (l >> 4)];
        qa1 = *(const bf16x8*)&Qs[row * 64 + 32 + 8 * (l >> 4)];
    }
    float m_r[4] = {-1e30f, -1e30f, -1e30f, -1e30f};
    float l_r[4] = {0.f, 0.f, 0.f, 0.f};
    f32x4 acc_o[4] = {};
    const int klo = (i0 >= 128) ? (i0 - 64) : 0;
    int khi = (L < klo) ? klo : min(i0 + 63, L);

    for (int j0 = klo; j0 <= khi; j0 += 64) {
        __syncthreads();
        {
            const int r = tid >> 3, c8 = (tid & 7) * 8;
            #pragma unroll
            for (int q = 0; q < 2; ++q) {
                const int row = r + 32 * q;
                *(uint4*)&Ks[row * 64 + c8] =
                    *(const uint4*)&QKV[(tb + j0 + row) * 1536 + 512 + h * 64 + c8];
                uint4 vv = *(const uint4*)&QKV[(tb + j0 + row) * 1536 + 1024 + h * 64 + c8];
                const u16* vs = (const u16*)&vv;
                #pragma unroll
                for (int e = 0; e < 8; ++e) Vt[(c8 + e) * 64 + row] = vs[e];
            }
        }
        __syncthreads();
        f32x4 s[4];
        #pragma unroll
        for (int f = 0; f < 4; ++f) {
            f32x4 z = {0.f, 0.f, 0.f, 0.f};
            bf16x8 kb0 = *(const bf16x8*)&Ks[(f * 16 + (l & 15)) * 64 + 8 * (l >> 4)];
            bf16x8 kb1 = *(const bf16x8*)&Ks[(f * 16 + (l & 15)) * 64 + 32 + 8 * (l >> 4)];
            z = MFMA16(qa0, kb0, z);
            z = MFMA16(qa1, kb1, z);
            s[f] = z;
        }
        float pm[4];
        #pragma unroll
        for (int r = 0; r < 4; ++r) {
            const int i_r = i0 + 16 * w + (l >> 4) * 4 + r;
            float mx = -__builtin_inff();
            #pragma unroll
            for (int f = 0; f < 4; ++f) {
                const int j = j0 + f * 16 + (l & 15);
                float sv = s[f][r] * 0.125f;
                const bool ok = (i_r >= L) ? (j == klo)
                              : (j <= i_r && (i_r <= 64 || j >= i_r - 64));
                sv = ok ? sv : -__builtin_inff();
                s[f][r] = sv;
                mx = fmaxf(mx, sv);
            }
            pm[r] = mx;
        }
        #pragma unroll
        for (int d = 1; d < 16; d <<= 1)
            #pragma unroll
            for (int r = 0; r < 4; ++r) pm[r] = fmaxf(pm[r], __shfl_xor(pm[r], d, 64));
        float sc[4];
        #pragma unroll
        for (int r = 0; r < 4; ++r) {
            const float mn = fmaxf(m_r[r], fmaxf(pm[r], -1e30f));
            sc[r] = __expf(m_r[r] - mn);
            m_r[r] = mn;
            l_r[r] *= sc[r];
        }
        #pragma unroll
        for (int f = 0; f < 4; ++f)
            #pragma unroll
            for (int r = 0; r < 4; ++r) acc_o[f][r] *= sc[r];
        float ps[4] = {0.f, 0.f, 0.f, 0.f};
        #pragma unroll
        for (int f = 0; f < 4; ++f)
            #pragma unroll
            for (int r = 0; r < 4; ++r) {
                const float p = __expf(s[f][r] - m_r[r]);
                s[f][r] = p;
                ps[r] += p;
            }
        #pragma unroll
        for (int d = 1; d < 16; d <<= 1)
            #pragma unroll
            for (int r = 0; r < 4; ++r) ps[r] += __shfl_xor(ps[r], d, 64);
        #pragma unroll
        for (int r = 0; r < 4; ++r) l_r[r] += ps[r];
        #pragma unroll
        for (int f = 0; f < 4; ++f)
            #pragma unroll
            for (int r = 0; r < 4; ++r)
                Ps[w][((l >> 4) * 4 + r) * 64 + f * 16 + (l & 15)] = f2bf(s[f][r]);
        bf16x8 pa0 = *(const bf16x8*)&Ps[w][(l & 15) * 64 + 8 * (l >> 4)];
        bf16x8 pa1 = *(const bf16x8*)&Ps[w][(l & 15) * 64 + 32 + 8 * (l >> 4)];
        #pragma unroll
        for (int f = 0; f < 4; ++f) {
            bf16x8 vb0 = *(const bf16x8*)&Vt[(f * 16 + (l & 15)) * 64 + 8 * (l >> 4)];
            bf16x8 vb1 = *(const bf16x8*)&Vt[(f * 16 + (l & 15)) * 64 + 32 + 8 * (l >> 4)];
            acc_o[f] = MFMA16(pa0, vb0, acc_o[f]);
            acc_o[f] = MFMA16(pa1, vb1, acc_o[f]);
        }
    }
    #pragma unroll
    for (int r = 0; r < 4; ++r) {
        const float inv = 1.f / l_r[r];
        const int row = i0 + 16 * w + (l >> 4) * 4 + r;
        if (row != L) {
            #pragma unroll
            for (int f = 0; f < 4; ++f)
                CTX[(tb + row) * 512 + h * 64 + f * 16 + (l & 15)] = f2bf(acc_o[f][r] * inv);
        }
    }
}

// ---------------------------------------------------------------------------
// LayerNorm over D=512 (in-place on X); 1 wave/token, 4 tokens/block.
// Dead 4-token blocks (all rows > obs[b]) skipped.
// ---------------------------------------------------------------------------
__global__ __launch_bounds__(256) void ln_kernel(
    const float* __restrict__ Y, const float* __restrict__ gw,
    const float* __restrict__ bw, float* __restrict__ X, u16* __restrict__ Xb,
    const int* __restrict__ obs)
{
    const int tok0 = blockIdx.x * 4;
    if ((tok0 & 2047) > obs[tok0 >> 11]) return;
    const int tok = tok0 + (threadIdx.x >> 6);
    const int l = threadIdx.x & 63;
    const float* y = &Y[(size_t)tok * 512 + l * 8];
    f32x4 v0 = *(const f32x4*)y;
    f32x4 v1 = *(const f32x4*)(y + 4);
    float s = 0.f, sq = 0.f;
    #pragma unroll
    for (int e = 0; e < 4; ++e) {
        s += v0[e] + v1[e];
        sq += v0[e] * v0[e] + v1[e] * v1[e];
    }
    #pragma unroll
    for (int d = 1; d < 64; d <<= 1) {
        s += __shfl_xor(s, d, 64);
        sq += __shfl_xor(sq, d, 64);
    }
    const float mean = s * (1.f / 512.f);
    const float var = sq * (1.f / 512.f) - mean * mean;
    const float rstd = rsqrtf(var + 1e-5f);
    f32x4 o0, o1;
    union { u16 us[8]; uint4 u4; } pk;
    #pragma unroll
    for (int e = 0; e < 8; ++e) {
        const int d = l * 8 + e;
        const float xv = (e < 4) ? v0[e] : v1[e - 4];
        const float ov = (xv - mean) * rstd * gw[d] + bw[d];
        if (e < 4) o0[e] = ov; else o1[e - 4] = ov;
        pk.us[e] = f2bf(ov);
    }
    float* xo = &X[(size_t)tok * 512 + l * 8];
    *(f32x4*)xo = o0;
    *(f32x4*)(xo + 4) = o1;
    *(uint4*)&Xb[(size_t)tok * 512 + l * 8] = pk.u4;
}

__global__ void cast_bf16_kernel(const float* __restrict__ in, u16* __restrict__ out, int n) {
    const int i = (blockIdx.x * 256 + threadIdx.x) * 4;
    if (i + 3 < n) {
        f32x4 v = *(const f32x4*)&in[i];
        union { u16 us[4]; uint2 u2; } pk;
        #pragma unroll
        for (int e = 0; e < 4; ++e) pk.us[e] = f2bf(v[e]);
        *(uint2*)&out[i] = pk.u2;
    }
}

__global__ void transpose_cast(const float* __restrict__ W, u16* __restrict__ WT, int K, int N) {
    __shared__ float t[32][33];
    const int n0 = blockIdx.x * 32, k0 = blockIdx.y * 32;
    const int tx = threadIdx.x, ty = threadIdx.y;
    #pragma unroll
    for (int r = 0; r < 32; r += 8)
        t[ty + r][tx] = W[(size_t)(k0 + ty + r) * N + n0 + tx];
    __syncthreads();
    #pragma unroll
    for (int r = 0; r < 32; r += 8)
        WT[(size_t)(n0 + ty + r) * K + k0 + tx] = f2bf(t[tx][ty + r]);
}

__global__ void agg_partial(const float* __restrict__ X, float* __restrict__ part,
                            const int* __restrict__ obs) {
    const int b = blockIdx.y, c = blockIdx.x, d = threadIdx.x;
    const int L = obs[b];
    float s = 0.f;
    const int t0 = c * 128;
    int tend = t0 + 128;
    if (tend > L + 1) tend = L + 1;
    for (int t = t0; t < tend; ++t) s += X[((size_t)b * 2048 + t) * 512 + d];
    part[((size_t)b * 16 + c) * 512 + d] = s;
}

__global__ void agg_final(const float* __restrict__ part, float* __restrict__ out,
                          const int* __restrict__ obs) {
    const int b = blockIdx.x, d = threadIdx.x;
    float s = 0.f;
    #pragma unroll
    for (int c = 0; c < 16; ++c) s += part[((size_t)b * 16 + c) * 512 + d];
    out[b * 512 + d] = s / (float)(obs[b] + 1);
}

// ---------------------------------------------------------------------------
extern "C" void kernel_launch(void* const* d_in, const int* in_sizes, int n_in,
                              void* d_out, int out_size, void* d_ws, size_t ws_size,
                              hipStream_t stream)
{
    const int M = 32768;     // B*T
    const int nch = (ws_size >= (size_t)215 * 1024 * 1024) ? 1 : 4;
    const int CH = M / nch;          // rows per chunk
    const int BPC = 16 / nch;        // batches per chunk
    const float* traj = (const float*)d_in[0];
    const int* obs = (const int*)d_in[1];
    const float* w_in = (const float*)d_in[2];
    const float* b_in = (const float*)d_in[3];

    char* base = (char*)d_ws;
    size_t off = 0;
    auto carve = [&](size_t bytes) -> void* {
        void* p = base + off;
        off += (bytes + 255) & ~(size_t)255;
        return p;
    };
    u16* U     = (u16*)carve((size_t)CH * 2048 * 2);
    u16* Xb    = (u16*)carve((size_t)M * 512 * 2);
    float* X   = (float*)carve((size_t)M * 512 * 4);
    float* part = (float*)carve((size_t)16 * 16 * 512 * 4);
    u16* wTin  = (u16*)carve((size_t)512 * 512 * 2);
    u16* wqkv  = (u16*)carve((size_t)1536 * 512 * 2);
    u16* wo    = (u16*)carve((size_t)512 * 512 * 2);
    u16* wff1  = (u16*)carve((size_t)2048 * 512 * 2);
    u16* wff2  = (u16*)carve((size_t)512 * 2048 * 2);

    dim3 tb32(32, 8);
    transpose_cast<<<dim3(16, 16), tb32, 0, stream>>>(w_in, wTin, 512, 512);

    for (int c = 0; c < nch; ++c) {
        cast_bf16_kernel<<<(CH * 512) / 1024, 256, 0, stream>>>(
            traj + (size_t)c * CH * 512, U, CH * 512);
        gemm_bf16<0><<<dim3(4, CH / 128), 256, 0, stream>>>(
            U, wTin, b_in, X + (size_t)c * CH * 512, Xb + (size_t)c * CH * 512,
            nullptr, obs + c * BPC, CH, 512, 512);
    }

    for (int lyr = 0; lyr < 4; ++lyr) {
        const int bi = 4 + 12 * lyr;
        transpose_cast<<<dim3(48, 16), tb32, 0, stream>>>((const float*)d_in[bi + 0], wqkv, 512, 1536);
        transpose_cast<<<dim3(16, 16), tb32, 0, stream>>>((const float*)d_in[bi + 2], wo, 512, 512);
        transpose_cast<<<dim3(64, 16), tb32, 0, stream>>>((const float*)d_in[bi + 4], wff1, 512, 2048);
        transpose_cast<<<dim3(16, 64), tb32, 0, stream>>>((const float*)d_in[bi + 6], wff2, 2048, 512);
        const float* b_qkv = (const float*)d_in[bi + 1];
        const float* b_o   = (const float*)d_in[bi + 3];
        const float* b_ff1 = (const float*)d_in[bi + 5];
        const float* b_ff2 = (const float*)d_in[bi + 7];
        const float* ln1g  = (const float*)d_in[bi + 8];
        const float* ln1b  = (const float*)d_in[bi + 9];
        const float* ln2g  = (const float*)d_in[bi + 10];
        const float* ln2b  = (const float*)d_in[bi + 11];

        for (int c = 0; c < nch; ++c) {
            gemm_bf16<1><<<dim3(12, CH / 128), 256, 0, stream>>>(
                Xb + (size_t)c * CH * 512, wqkv, b_qkv, nullptr, U, nullptr,
                obs + c * BPC, CH, 1536, 512);
            attn_kernel<<<dim3(33, 8, BPC), 256, 0, stream>>>(
                U, Xb + (size_t)c * CH * 512, obs + c * BPC);
        }
        gemm_bf16<2><<<dim3(4, M / 128), 256, 0, stream>>>(
            Xb, wo, b_o, X, nullptr, X, obs, M, 512, 512);
        ln_kernel<<<M / 4, 256, 0, stream>>>(X, ln1g, ln1b, X, Xb, obs);
        for (int c = 0; c < nch; ++c) {
            gemm_bf16<3><<<dim3(16, CH / 128), 256, 0, stream>>>(
                Xb + (size_t)c * CH * 512, wff1, b_ff1, nullptr, U, nullptr,
                obs + c * BPC, CH, 2048, 512);
            gemm_bf16<2><<<dim3(4, CH / 128), 256, 0, stream>>>(
                U, wff2, b_ff2, X + (size_t)c * CH * 512, nullptr,
                X + (size_t)c * CH * 512, obs + c * BPC, CH, 512, 2048);
        }
        ln_kernel<<<M / 4, 256, 0, stream>>>(X, ln2g, ln2b, X, Xb, obs);
    }

    agg_partial<<<dim3(16, 16), 512, 0, stream>>>(X, part, obs);
    agg_final<<<16, 512, 0, stream>>>(part, (float*)d_out, obs);
}

// Round 5
// 1708.697 us; speedup vs baseline: 2.3009x; 1.1736x over previous
//
#include <hip/hip_runtime.h>

typedef unsigned short u16;
typedef unsigned int u32;
typedef __bf16 bf16x8 __attribute__((ext_vector_type(8)));
typedef float f32x4 __attribute__((ext_vector_type(4)));

#define MFMA16(a, b, c) __builtin_amdgcn_mfma_f32_16x16x32_bf16((a), (b), (c), 0, 0, 0)

__device__ __forceinline__ u16 f2bf(float x) {
    union { float f; u32 u; } v; v.f = x;
    u32 r = v.u + 0x7fffu + ((v.u >> 16) & 1u);
    return (u16)(r >> 16);
}
__device__ __forceinline__ float bf2f(u16 x) {
    union { u32 u; float f; } v; v.u = ((u32)x) << 16; return v.f;
}

typedef const __attribute__((address_space(1))) u32* gas1_t;
typedef __attribute__((address_space(3))) u32* las3_t;
__device__ __forceinline__ void g2lds16(const void* g, void* l) {
    __builtin_amdgcn_global_load_lds((gas1_t)g, (las3_t)l, 16, 0, 0);
}

// ---------------------------------------------------------------------------
// GEMM: C(M,N) = A(M,K)bf16 @ BT(N,K)bf16^T + bias, fused epilogues.
// MODE 0: += PE[row&2047][col] (via aux ptr); write f32 + bf16  (in-proj)
// MODE 1: write bf16                     (qkv)
// MODE 2: += resid; write f32 (in-place OK)   (o-proj / ff2)
// MODE 3: relu; write bf16               (ff1)
// m97 fragment layout + bijective XCD swizzle + dead-tile skip + T3 2-phase
// double-buffered staging (STAGE(next) overlaps compute(cur); one barrier
// per K-step whose implicit vmcnt(0)/lgkmcnt(0) drain makes handoff safe).
// ---------------------------------------------------------------------------
template <int MODE>
__global__ __launch_bounds__(256) void gemm_bf16(
    const u16* __restrict__ A, const u16* __restrict__ BT,
    const float* __restrict__ bias, float* __restrict__ outF,
    u16* __restrict__ outB, const float* __restrict__ aux,
    const int* __restrict__ obs,
    int M, int N, int K)
{
    __shared__ u16 As[2][128 * 32];
    __shared__ u16 Bs[2][128 * 32];
    const int tid = threadIdx.x;
    const int w = tid >> 6, l = tid & 63;
    // XCD-aware bijective swizzle (m204): contiguous wgid chunk per XCD.
    const int gx = gridDim.x;
    const int nwg = gx * gridDim.y;
    const int orig = blockIdx.y * gx + blockIdx.x;
    const int q8 = nwg >> 3, r8 = nwg & 7;
    const int xcd = orig & 7, loc = orig >> 3;
    const int wgid = (xcd < r8 ? xcd * (q8 + 1) : r8 * (q8 + 1) + (xcd - r8) * q8) + loc;
    const int bm = (wgid / gx) * 128, bn = (wgid % gx) * 128;
    // dead-tile skip: tile entirely above obs[batch] -> pad rows only.
    if ((bm & 2047) > obs[bm >> 11]) return;
    const int wr = (w >> 1) * 64, wc = (w & 1) * 64;
    const int larow = l >> 2, lacol = (l & 3) * 8;
    f32x4 acc[4][4] = {};

    const int r0a = 16 * w, r0b = 16 * (w + 4);
    const u16* Ap = &A[(size_t)(bm + larow) * K + lacol];
    const u16* Bp = &BT[(size_t)(bn + larow) * K + lacol];

    // prologue stage into buf 0
    {
        g2lds16(Ap + (size_t)r0a * K, &As[0][r0a * 32]);
        g2lds16(Bp + (size_t)r0a * K, &Bs[0][r0a * 32]);
        g2lds16(Ap + (size_t)r0b * K, &As[0][r0b * 32]);
        g2lds16(Bp + (size_t)r0b * K, &Bs[0][r0b * 32]);
    }
    __syncthreads();
    int cur = 0;
    const int nk = K >> 5;
    for (int ki = 0; ki < nk; ++ki) {
        if (ki + 1 < nk) {
            const int kt = (ki + 1) << 5;
            g2lds16(Ap + (size_t)r0a * K + kt, &As[cur ^ 1][r0a * 32]);
            g2lds16(Bp + (size_t)r0a * K + kt, &Bs[cur ^ 1][r0a * 32]);
            g2lds16(Ap + (size_t)r0b * K + kt, &As[cur ^ 1][r0b * 32]);
            g2lds16(Bp + (size_t)r0b * K + kt, &Bs[cur ^ 1][r0b * 32]);
        }
        bf16x8 af[4], bfr[4];
        #pragma unroll
        for (int i = 0; i < 4; ++i)
            af[i] = *(const bf16x8*)&As[cur][(wr + i * 16 + (l & 15)) * 32 + 8 * (l >> 4)];
        #pragma unroll
        for (int j = 0; j < 4; ++j)
            bfr[j] = *(const bf16x8*)&Bs[cur][(wc + j * 16 + (l & 15)) * 32 + 8 * (l >> 4)];
        #pragma unroll
        for (int i = 0; i < 4; ++i)
            #pragma unroll
            for (int j = 0; j < 4; ++j)
                acc[i][j] = MFMA16(af[i], bfr[j], acc[i][j]);
        __syncthreads();   // drains stage (vmcnt0) + ds_reads (lgkmcnt0), then barrier
        cur ^= 1;
    }

    const int r0 = bm + wr + (l >> 4) * 4;
    const int c0 = bn + wc + (l & 15);
    #pragma unroll
    for (int i = 0; i < 4; ++i) {
        #pragma unroll
        for (int j = 0; j < 4; ++j) {
            const int col = c0 + j * 16;
            const float bc = bias[col];
            #pragma unroll
            for (int r = 0; r < 4; ++r) {
                const int row = r0 + i * 16 + r;
                const size_t idx = (size_t)row * N + col;
                float val = acc[i][j][r] + bc;
                if constexpr (MODE == 0) {
                    val += aux[(size_t)(row & 2047) * 512 + col];   // PE table
                    outF[idx] = val;
                    outB[idx] = f2bf(val);
                } else if constexpr (MODE == 1) {
                    outB[idx] = f2bf(val);
                } else if constexpr (MODE == 2) {
                    outF[idx] = val + aux[idx];
                } else {
                    outB[idx] = f2bf(fmaxf(val, 0.f));
                }
            }
        }
    }
}

// ---------------------------------------------------------------------------
// PE table: PE[t][2p] = sin(t*fr(p)), PE[t][2p+1] = cos(t*fr(p)),
// fr(p) = exp(2p * -ln(10000)/512). 2048x512 f32 = 4 MB.
// ---------------------------------------------------------------------------
__global__ void pe_kernel(float* __restrict__ PE) {
    const int idx = blockIdx.x * 256 + threadIdx.x;   // t*256 + pair
    const int t = idx >> 8, p = idx & 255;
    const float fr = expf((float)(2 * p) * -0.017988946039015984f);
    const float arg = (float)t * fr;
    float s, c;
    sincosf(arg, &s, &c);
    float2 v = {s, c};
    *(float2*)&PE[(size_t)t * 512 + 2 * p] = v;
}

// ---------------------------------------------------------------------------
// Flash attention, two phases in one dispatch (unchanged from round 4).
// ---------------------------------------------------------------------------
__global__ __launch_bounds__(256) void attn_kernel(
    const u16* __restrict__ QKV, u16* __restrict__ CTX, const int* __restrict__ obs)
{
    __shared__ u16 Qs[64 * 64];
    __shared__ u16 Ks[64 * 64];
    __shared__ u16 Vt[64 * 64];
    __shared__ u16 Ps[4][16 * 64];
    const int b = blockIdx.z, h = blockIdx.y;
    const int L = obs[b];
    const int tid = threadIdx.x, w = tid >> 6, l = tid & 63;
    const size_t tb = (size_t)b * 2048;

    if (blockIdx.x != 32 && (int)blockIdx.x * 64 > L) return;  // dead q-tile

    if (blockIdx.x == 32) {
        // ---- Phase B: row L, keys [0, L] ----
        float* pP = (float*)Ks;
        float* oW = (float*)Vt;
        float* mW = (float*)Ps;
        u16 q16[64];
        #pragma unroll
        for (int dd = 0; dd < 8; ++dd)
            *(uint4*)&q16[dd * 8] = *(const uint4*)&QKV[(tb + L) * 1536 + h * 64 + dd * 8];
        float m = -3.0e38f, lsum = 0.f, oacc = 0.f;
        for (int j0 = w * 64; j0 <= L; j0 += 256) {
            const int j = j0 + l;
            const bool val = (j <= L);
            float s = -3.0e38f;
            if (val) {
                s = 0.f;
                const u16* kp = &QKV[(tb + j) * 1536 + 512 + h * 64];
                #pragma unroll
                for (int dd = 0; dd < 8; ++dd) {
                    uint4 kk = *(const uint4*)&kp[dd * 8];
                    const u16* ke = (const u16*)&kk;
                    #pragma unroll
                    for (int e = 0; e < 8; ++e)
                        s += bf2f(q16[dd * 8 + e]) * bf2f(ke[e]);
                }
                s *= 0.125f;
            }
            float mx = s;
            #pragma unroll
            for (int d = 1; d < 64; d <<= 1) mx = fmaxf(mx, __shfl_xor(mx, d, 64));
            const float mn = fmaxf(m, mx);
            const float sc = __expf(m - mn);
            m = mn;
            const float p = val ? __expf(s - mn) : 0.f;
            float ps = p;
            #pragma unroll
            for (int d = 1; d < 64; d <<= 1) ps += __shfl_xor(ps, d, 64);
            lsum = lsum * sc + ps;
            oacc *= sc;
            pP[w * 64 + l] = p;
            __builtin_amdgcn_wave_barrier();
            #pragma unroll 4
            for (int jj = 0; jj < 64; ++jj) {
                const int rr = (j0 + jj <= L) ? (j0 + jj) : L;
                oacc += pP[w * 64 + jj] * bf2f(QKV[(tb + rr) * 1536 + 1024 + h * 64 + l]);
            }
            __builtin_amdgcn_wave_barrier();
        }
        oW[w * 64 + l] = oacc;
        if (l == 0) { mW[w] = m; mW[8 + w] = lsum; }
        __syncthreads();
        if (w == 0) {
            float mstar = fmaxf(fmaxf(mW[0], mW[1]), fmaxf(mW[2], mW[3]));
            float ot = 0.f, lt = 0.f;
            #pragma unroll
            for (int ww = 0; ww < 4; ++ww) {
                const float sc = __expf(mW[ww] - mstar);
                ot += sc * oW[ww * 64 + l];
                lt += sc * mW[8 + ww];
            }
            CTX[(tb + L) * 512 + h * 64 + l] = f2bf(ot / lt);
        }
        return;
    }

    // ---- Phase A ----
    const int i0 = blockIdx.x * 64;
    {
        const int r = tid >> 3, c8 = (tid & 7) * 8;
        #pragma unroll
        for (int q = 0; q < 2; ++q) {
            const int row = r + 32 * q;
            *(uint4*)&Qs[row * 64 + c8] =
                *(const uint4*)&QKV[(tb + i0 + row) * 1536 + h * 64 + c8];
        }
    }
    __syncthreads();
    bf16x8 qa0, qa1;
    {
        const int row = 16 * w + (l & 15);
        qa0 = *(const bf16x8*)&Qs[row * 64 + 8 * (l >> 4)];
        qa1 = *(const bf16x8*)&Qs[row * 64 + 32 + 8 * (l >> 4)];
    }
    float m_r[4] = {-1e30f, -1e30f, -1e30f, -1e30f};
    float l_r[4] = {0.f, 0.f, 0.f, 0.f};
    f32x4 acc_o[4] = {};
    const int klo = (i0 >= 128) ? (i0 - 64) : 0;
    int khi = (L < klo) ? klo : min(i0 + 63, L);

    for (int j0 = klo; j0 <= khi; j0 += 64) {
        __syncthreads();
        {
            const int r = tid >> 3, c8 = (tid & 7) * 8;
            #pragma unroll
            for (int q = 0; q < 2; ++q) {
                const int row = r + 32 * q;
                *(uint4*)&Ks[row * 64 + c8] =
                    *(const uint4*)&QKV[(tb + j0 + row) * 1536 + 512 + h * 64 + c8];
                uint4 vv = *(const uint4*)&QKV[(tb + j0 + row) * 1536 + 1024 + h * 64 + c8];
                const u16* vs = (const u16*)&vv;
                #pragma unroll
                for (int e = 0; e < 8; ++e) Vt[(c8 + e) * 64 + row] = vs[e];
            }
        }
        __syncthreads();
        f32x4 s[4];
        #pragma unroll
        for (int f = 0; f < 4; ++f) {
            f32x4 z = {0.f, 0.f, 0.f, 0.f};
            bf16x8 kb0 = *(const bf16x8*)&Ks[(f * 16 + (l & 15)) * 64 + 8 * (l >> 4)];
            bf16x8 kb1 = *(const bf16x8*)&Ks[(f * 16 + (l & 15)) * 64 + 32 + 8 * (l >> 4)];
            z = MFMA16(qa0, kb0, z);
            z = MFMA16(qa1, kb1, z);
            s[f] = z;
        }
        float pm[4];
        #pragma unroll
        for (int r = 0; r < 4; ++r) {
            const int i_r = i0 + 16 * w + (l >> 4) * 4 + r;
            float mx = -__builtin_inff();
            #pragma unroll
            for (int f = 0; f < 4; ++f) {
                const int j = j0 + f * 16 + (l & 15);
                float sv = s[f][r] * 0.125f;
                const bool ok = (i_r >= L) ? (j == klo)
                              : (j <= i_r && (i_r <= 64 || j >= i_r - 64));
                sv = ok ? sv : -__builtin_inff();
                s[f][r] = sv;
                mx = fmaxf(mx, sv);
            }
            pm[r] = mx;
        }
        #pragma unroll
        for (int d = 1; d < 16; d <<= 1)
            #pragma unroll
            for (int r = 0; r < 4; ++r) pm[r] = fmaxf(pm[r], __shfl_xor(pm[r], d, 64));
        float sc[4];
        #pragma unroll
        for (int r = 0; r < 4; ++r) {
            const float mn = fmaxf(m_r[r], fmaxf(pm[r], -1e30f));
            sc[r] = __expf(m_r[r] - mn);
            m_r[r] = mn;
            l_r[r] *= sc[r];
        }
        #pragma unroll
        for (int f = 0; f < 4; ++f)
            #pragma unroll
            for (int r = 0; r < 4; ++r) acc_o[f][r] *= sc[r];
        float ps[4] = {0.f, 0.f, 0.f, 0.f};
        #pragma unroll
        for (int f = 0; f < 4; ++f)
            #pragma unroll
            for (int r = 0; r < 4; ++r) {
                const float p = __expf(s[f][r] - m_r[r]);
                s[f][r] = p;
                ps[r] += p;
            }
        #pragma unroll
        for (int d = 1; d < 16; d <<= 1)
            #pragma unroll
            for (int r = 0; r < 4; ++r) ps[r] += __shfl_xor(ps[r], d, 64);
        #pragma unroll
        for (int r = 0; r < 4; ++r) l_r[r] += ps[r];
        #pragma unroll
        for (int f = 0; f < 4; ++f)
            #pragma unroll
            for (int r = 0; r < 4; ++r)
                Ps[w][((l >> 4) * 4 + r) * 64 + f * 16 + (l & 15)] = f2bf(s[f][r]);
        bf16x8 pa0 = *(const bf16x8*)&Ps[w][(l & 15) * 64 + 8 * (l >> 4)];
        bf16x8 pa1 = *(const bf16x8*)&Ps[w][(l & 15) * 64 + 32 + 8 * (l >> 4)];
        #pragma unroll
        for (int f = 0; f < 4; ++f) {
            bf16x8 vb0 = *(const bf16x8*)&Vt[(f * 16 + (l & 15)) * 64 + 8 * (l >> 4)];
            bf16x8 vb1 = *(const bf16x8*)&Vt[(f * 16 + (l & 15)) * 64 + 32 + 8 * (l >> 4)];
            acc_o[f] = MFMA16(pa0, vb0, acc_o[f]);
            acc_o[f] = MFMA16(pa1, vb1, acc_o[f]);
        }
    }
    #pragma unroll
    for (int r = 0; r < 4; ++r) {
        const float inv = 1.f / l_r[r];
        const int row = i0 + 16 * w + (l >> 4) * 4 + r;
        if (row != L) {
            #pragma unroll
            for (int f = 0; f < 4; ++f)
                CTX[(tb + row) * 512 + h * 64 + f * 16 + (l & 15)] = f2bf(acc_o[f][r] * inv);
        }
    }
}

// ---------------------------------------------------------------------------
// LayerNorm over D=512 (in-place on X); 1 wave/token, dead blocks skipped.
// ---------------------------------------------------------------------------
__global__ __launch_bounds__(256) void ln_kernel(
    const float* __restrict__ Y, const float* __restrict__ gw,
    const float* __restrict__ bw, float* __restrict__ X, u16* __restrict__ Xb,
    const int* __restrict__ obs)
{
    const int tok0 = blockIdx.x * 4;
    if ((tok0 & 2047) > obs[tok0 >> 11]) return;
    const int tok = tok0 + (threadIdx.x >> 6);
    const int l = threadIdx.x & 63;
    const float* y = &Y[(size_t)tok * 512 + l * 8];
    f32x4 v0 = *(const f32x4*)y;
    f32x4 v1 = *(const f32x4*)(y + 4);
    float s = 0.f, sq = 0.f;
    #pragma unroll
    for (int e = 0; e < 4; ++e) {
        s += v0[e] + v1[e];
        sq += v0[e] * v0[e] + v1[e] * v1[e];
    }
    #pragma unroll
    for (int d = 1; d < 64; d <<= 1) {
        s += __shfl_xor(s, d, 64);
        sq += __shfl_xor(sq, d, 64);
    }
    const float mean = s * (1.f / 512.f);
    const float var = sq * (1.f / 512.f) - mean * mean;
    const float rstd = rsqrtf(var + 1e-5f);
    f32x4 o0, o1;
    union { u16 us[8]; uint4 u4; } pk;
    #pragma unroll
    for (int e = 0; e < 8; ++e) {
        const int d = l * 8 + e;
        const float xv = (e < 4) ? v0[e] : v1[e - 4];
        const float ov = (xv - mean) * rstd * gw[d] + bw[d];
        if (e < 4) o0[e] = ov; else o1[e - 4] = ov;
        pk.us[e] = f2bf(ov);
    }
    float* xo = &X[(size_t)tok * 512 + l * 8];
    *(f32x4*)xo = o0;
    *(f32x4*)(xo + 4) = o1;
    *(uint4*)&Xb[(size_t)tok * 512 + l * 8] = pk.u4;
}

__global__ void cast_bf16_kernel(const float* __restrict__ in, u16* __restrict__ out, int n) {
    const int i = (blockIdx.x * 256 + threadIdx.x) * 4;
    if (i + 3 < n) {
        f32x4 v = *(const f32x4*)&in[i];
        union { u16 us[4]; uint2 u2; } pk;
        #pragma unroll
        for (int e = 0; e < 4; ++e) pk.us[e] = f2bf(v[e]);
        *(uint2*)&out[i] = pk.u2;
    }
}

__global__ void transpose_cast(const float* __restrict__ W, u16* __restrict__ WT, int K, int N) {
    __shared__ float t[32][33];
    const int n0 = blockIdx.x * 32, k0 = blockIdx.y * 32;
    const int tx = threadIdx.x, ty = threadIdx.y;
    #pragma unroll
    for (int r = 0; r < 32; r += 8)
        t[ty + r][tx] = W[(size_t)(k0 + ty + r) * N + n0 + tx];
    __syncthreads();
    #pragma unroll
    for (int r = 0; r < 32; r += 8)
        WT[(size_t)(n0 + ty + r) * K + k0 + tx] = f2bf(t[tx][ty + r]);
}

// All four per-layer weights transposed in one launch (3072 tile-blocks).
__global__ void transpose_layer(
    const float* __restrict__ wq, const float* __restrict__ wo_,
    const float* __restrict__ wf1, const float* __restrict__ wf2,
    u16* __restrict__ dq, u16* __restrict__ dok,
    u16* __restrict__ df1, u16* __restrict__ df2)
{
    __shared__ float t[32][33];
    int id = blockIdx.x;
    const float* W; u16* D; int K, N;
    if (id < 768)       { W = wq;  D = dq;  K = 512;  N = 1536; }
    else if (id < 1024) { W = wo_; D = dok; K = 512;  N = 512;  id -= 768; }
    else if (id < 2048) { W = wf1; D = df1; K = 512;  N = 2048; id -= 1024; }
    else                { W = wf2; D = df2; K = 2048; N = 512;  id -= 2048; }
    const int nx = N >> 5;
    const int n0 = (id % nx) * 32, k0 = (id / nx) * 32;
    const int tx = threadIdx.x, ty = threadIdx.y;
    #pragma unroll
    for (int r = 0; r < 32; r += 8)
        t[ty + r][tx] = W[(size_t)(k0 + ty + r) * N + n0 + tx];
    __syncthreads();
    #pragma unroll
    for (int r = 0; r < 32; r += 8)
        D[(size_t)(n0 + ty + r) * K + k0 + tx] = f2bf(t[tx][ty + r]);
}

__global__ void agg_partial(const float* __restrict__ X, float* __restrict__ part,
                            const int* __restrict__ obs) {
    const int b = blockIdx.y, c = blockIdx.x, d = threadIdx.x;
    const int L = obs[b];
    float s = 0.f;
    const int t0 = c * 128;
    int tend = t0 + 128;
    if (tend > L + 1) tend = L + 1;
    for (int t = t0; t < tend; ++t) s += X[((size_t)b * 2048 + t) * 512 + d];
    part[((size_t)b * 16 + c) * 512 + d] = s;
}

__global__ void agg_final(const float* __restrict__ part, float* __restrict__ out,
                          const int* __restrict__ obs) {
    const int b = blockIdx.x, d = threadIdx.x;
    float s = 0.f;
    #pragma unroll
    for (int c = 0; c < 16; ++c) s += part[((size_t)b * 16 + c) * 512 + d];
    out[b * 512 + d] = s / (float)(obs[b] + 1);
}

// ---------------------------------------------------------------------------
// Workspace (~208 MB, known-safe since round-4 used 237 MB successfully):
//   U   100.7 MB (traj-bf16 / full-M QKV / FF-hidden half-chunks)
//   Xb  32 MB, X 64 MB, PE 4 MB, part 0.5 MB, weights 6.5 MB
// ---------------------------------------------------------------------------
extern "C" void kernel_launch(void* const* d_in, const int* in_sizes, int n_in,
                              void* d_out, int out_size, void* d_ws, size_t ws_size,
                              hipStream_t stream)
{
    const int M = 32768;        // B*T
    const int FCH = 16384;      // FF chunk rows (8 batches)
    const float* traj = (const float*)d_in[0];
    const int* obs = (const int*)d_in[1];
    const float* w_in = (const float*)d_in[2];
    const float* b_in = (const float*)d_in[3];

    char* base = (char*)d_ws;
    size_t off = 0;
    auto carve = [&](size_t bytes) -> void* {
        void* p = base + off;
        off += (bytes + 255) & ~(size_t)255;
        return p;
    };
    u16* U     = (u16*)carve((size_t)M * 1536 * 2);     // 100.7 MB
    u16* Xb    = (u16*)carve((size_t)M * 512 * 2);      // 32 MB
    float* X   = (float*)carve((size_t)M * 512 * 4);    // 64 MB
    float* PE  = (float*)carve((size_t)2048 * 512 * 4); // 4 MB
    float* part = (float*)carve((size_t)16 * 16 * 512 * 4);
    u16* wTin  = (u16*)carve((size_t)512 * 512 * 2);
    u16* wqkv  = (u16*)carve((size_t)1536 * 512 * 2);
    u16* wo    = (u16*)carve((size_t)512 * 512 * 2);
    u16* wff1  = (u16*)carve((size_t)2048 * 512 * 2);
    u16* wff2  = (u16*)carve((size_t)512 * 2048 * 2);

    dim3 tb32(32, 8);
    pe_kernel<<<2048, 256, 0, stream>>>(PE);
    transpose_cast<<<dim3(16, 16), tb32, 0, stream>>>(w_in, wTin, 512, 512);

    // input projection: X = traj @ w_in + b_in + PE  (full M through U)
    cast_bf16_kernel<<<(M * 512) / 1024, 256, 0, stream>>>(traj, U, M * 512);
    gemm_bf16<0><<<dim3(4, M / 128), 256, 0, stream>>>(
        U, wTin, b_in, X, Xb, PE, obs, M, 512, 512);

    for (int lyr = 0; lyr < 4; ++lyr) {
        const int bi = 4 + 12 * lyr;
        transpose_layer<<<3072, tb32, 0, stream>>>(
            (const float*)d_in[bi + 0], (const float*)d_in[bi + 2],
            (const float*)d_in[bi + 4], (const float*)d_in[bi + 6],
            wqkv, wo, wff1, wff2);
        const float* b_qkv = (const float*)d_in[bi + 1];
        const float* b_o   = (const float*)d_in[bi + 3];
        const float* b_ff1 = (const float*)d_in[bi + 5];
        const float* b_ff2 = (const float*)d_in[bi + 7];
        const float* ln1g  = (const float*)d_in[bi + 8];
        const float* ln1b  = (const float*)d_in[bi + 9];
        const float* ln2g  = (const float*)d_in[bi + 10];
        const float* ln2b  = (const float*)d_in[bi + 11];

        // QKV full-M through U; attention ctx overwrites Xb.
        gemm_bf16<1><<<dim3(12, M / 128), 256, 0, stream>>>(
            Xb, wqkv, b_qkv, nullptr, U, nullptr, obs, M, 1536, 512);
        attn_kernel<<<dim3(33, 8, 16), 256, 0, stream>>>(U, Xb, obs);
        gemm_bf16<2><<<dim3(4, M / 128), 256, 0, stream>>>(
            Xb, wo, b_o, X, nullptr, X, obs, M, 512, 512);
        ln_kernel<<<M / 4, 256, 0, stream>>>(X, ln1g, ln1b, X, Xb, obs);
        // FF in 2 chunks of 16384 rows through U.
        for (int c = 0; c < 2; ++c) {
            gemm_bf16<3><<<dim3(16, FCH / 128), 256, 0, stream>>>(
                Xb + (size_t)c * FCH * 512, wff1, b_ff1, nullptr, U, nullptr,
                obs + c * 8, FCH, 2048, 512);
            gemm_bf16<2><<<dim3(4, FCH / 128), 256, 0, stream>>>(
                U, wff2, b_ff2, X + (size_t)c * FCH * 512, nullptr,
                X + (size_t)c * FCH * 512, obs + c * 8, FCH, 512, 2048);
        }
        ln_kernel<<<M / 4, 256, 0, stream>>>(X, ln2g, ln2b, X, Xb, obs);
    }

    agg_partial<<<dim3(16, 16), 512, 0, stream>>>(X, part, obs);
    agg_final<<<16, 512, 0, stream>>>(part, (float*)d_out, obs);
}

// Round 6
// 1629.573 us; speedup vs baseline: 2.4126x; 1.0486x over previous
//
#include <hip/hip_runtime.h>

typedef unsigned short u16;
typedef unsigned int u32;
typedef __bf16 bf16x8 __attribute__((ext_vector_type(8)));
typedef float f32x4 __attribute__((ext_vector_type(4)));

#define MFMA16(a, b, c) __builtin_amdgcn_mfma_f32_16x16x32_bf16((a), (b), (c), 0, 0, 0)

__device__ __forceinline__ u16 f2bf(float x) {
    union { float f; u32 u; } v; v.f = x;
    u32 r = v.u + 0x7fffu + ((v.u >> 16) & 1u);
    return (u16)(r >> 16);
}
__device__ __forceinline__ float bf2f(u16 x) {
    union { u32 u; float f; } v; v.u = ((u32)x) << 16; return v.f;
}

typedef const __attribute__((address_space(1))) u32* gas1_t;
typedef __attribute__((address_space(3))) u32* las3_t;
__device__ __forceinline__ void g2lds16(const void* g, void* l) {
    __builtin_amdgcn_global_load_lds((gas1_t)g, (las3_t)l, 16, 0, 0);
}

// ---------------------------------------------------------------------------
// GEMM (unchanged from round 5): m97 fragment layout + XCD swizzle +
// dead-tile skip + 2-phase double-buffered staging.
// ---------------------------------------------------------------------------
template <int MODE>
__global__ __launch_bounds__(256) void gemm_bf16(
    const u16* __restrict__ A, const u16* __restrict__ BT,
    const float* __restrict__ bias, float* __restrict__ outF,
    u16* __restrict__ outB, const float* __restrict__ aux,
    const int* __restrict__ obs,
    int M, int N, int K)
{
    __shared__ u16 As[2][128 * 32];
    __shared__ u16 Bs[2][128 * 32];
    const int tid = threadIdx.x;
    const int w = tid >> 6, l = tid & 63;
    const int gx = gridDim.x;
    const int nwg = gx * gridDim.y;
    const int orig = blockIdx.y * gx + blockIdx.x;
    const int q8 = nwg >> 3, r8 = nwg & 7;
    const int xcd = orig & 7, loc = orig >> 3;
    const int wgid = (xcd < r8 ? xcd * (q8 + 1) : r8 * (q8 + 1) + (xcd - r8) * q8) + loc;
    const int bm = (wgid / gx) * 128, bn = (wgid % gx) * 128;
    if ((bm & 2047) > obs[bm >> 11]) return;
    const int wr = (w >> 1) * 64, wc = (w & 1) * 64;
    const int larow = l >> 2, lacol = (l & 3) * 8;
    f32x4 acc[4][4] = {};

    const int r0a = 16 * w, r0b = 16 * (w + 4);
    const u16* Ap = &A[(size_t)(bm + larow) * K + lacol];
    const u16* Bp = &BT[(size_t)(bn + larow) * K + lacol];

    {
        g2lds16(Ap + (size_t)r0a * K, &As[0][r0a * 32]);
        g2lds16(Bp + (size_t)r0a * K, &Bs[0][r0a * 32]);
        g2lds16(Ap + (size_t)r0b * K, &As[0][r0b * 32]);
        g2lds16(Bp + (size_t)r0b * K, &Bs[0][r0b * 32]);
    }
    __syncthreads();
    int cur = 0;
    const int nk = K >> 5;
    for (int ki = 0; ki < nk; ++ki) {
        if (ki + 1 < nk) {
            const int kt = (ki + 1) << 5;
            g2lds16(Ap + (size_t)r0a * K + kt, &As[cur ^ 1][r0a * 32]);
            g2lds16(Bp + (size_t)r0a * K + kt, &Bs[cur ^ 1][r0a * 32]);
            g2lds16(Ap + (size_t)r0b * K + kt, &As[cur ^ 1][r0b * 32]);
            g2lds16(Bp + (size_t)r0b * K + kt, &Bs[cur ^ 1][r0b * 32]);
        }
        bf16x8 af[4], bfr[4];
        #pragma unroll
        for (int i = 0; i < 4; ++i)
            af[i] = *(const bf16x8*)&As[cur][(wr + i * 16 + (l & 15)) * 32 + 8 * (l >> 4)];
        #pragma unroll
        for (int j = 0; j < 4; ++j)
            bfr[j] = *(const bf16x8*)&Bs[cur][(wc + j * 16 + (l & 15)) * 32 + 8 * (l >> 4)];
        #pragma unroll
        for (int i = 0; i < 4; ++i)
            #pragma unroll
            for (int j = 0; j < 4; ++j)
                acc[i][j] = MFMA16(af[i], bfr[j], acc[i][j]);
        __syncthreads();
        cur ^= 1;
    }

    const int r0 = bm + wr + (l >> 4) * 4;
    const int c0 = bn + wc + (l & 15);
    #pragma unroll
    for (int i = 0; i < 4; ++i) {
        #pragma unroll
        for (int j = 0; j < 4; ++j) {
            const int col = c0 + j * 16;
            const float bc = bias[col];
            #pragma unroll
            for (int r = 0; r < 4; ++r) {
                const int row = r0 + i * 16 + r;
                const size_t idx = (size_t)row * N + col;
                float val = acc[i][j][r] + bc;
                if constexpr (MODE == 0) {
                    val += aux[(size_t)(row & 2047) * 512 + col];
                    outF[idx] = val;
                    outB[idx] = f2bf(val);
                } else if constexpr (MODE == 1) {
                    outB[idx] = f2bf(val);
                } else if constexpr (MODE == 2) {
                    outF[idx] = val + aux[idx];
                } else {
                    outB[idx] = f2bf(fmaxf(val, 0.f));
                }
            }
        }
    }
}

__global__ void pe_kernel(float* __restrict__ PE) {
    const int idx = blockIdx.x * 256 + threadIdx.x;
    const int t = idx >> 8, p = idx & 255;
    const float fr = expf((float)(2 * p) * -0.017988946039015984f);
    const float arg = (float)t * fr;
    float s, c;
    sincosf(arg, &s, &c);
    float2 v = {s, c};
    *(float2*)&PE[(size_t)t * 512 + 2 * p] = v;
}

// ---------------------------------------------------------------------------
// Flash attention.
// Phase A (x<32): 64-row q-tile, banded keys, <=2 k-tiles. XOR-swizzled LDS
//   (granule g of each 128B row ^= row&7) -> 2-way reads instead of 16-way.
//   K staged via global_load_lds with INVERSE-swizzled global source (linear
//   LDS dest), V transposed-scatter with swizzle, Q frags direct from global.
// Phase B (x in [32,40)): row L; wave = one 64-key sub-chunk cc; partials
//   (m, lsum, o[64]) -> PB workspace; attn_merge combines.
// ---------------------------------------------------------------------------
__global__ __launch_bounds__(256) void attn_kernel(
    const u16* __restrict__ QKV, u16* __restrict__ CTX, const int* __restrict__ obs,
    float* __restrict__ PBm, float* __restrict__ PBl, float* __restrict__ PBo)
{
    __shared__ u16 Ks[64 * 64];
    __shared__ u16 Vt[64 * 64];
    __shared__ u16 Ps[4][16 * 64];
    const int b = blockIdx.z, h = blockIdx.y;
    const int L = obs[b];
    const int tid = threadIdx.x, w = tid >> 6, l = tid & 63;
    const size_t tb = (size_t)b * 2048;

    if (blockIdx.x >= 32) {
        // ---- Phase B: row L, wave-parallel sub-chunks of 64 keys ----
        const int cbase = (blockIdx.x - 32) * 4;
        if (cbase * 64 > L) return;
        const int cc = cbase + w;
        float* pP = (float*)Ks;       // [4][64]
        u16 q16[64];
        #pragma unroll
        for (int dd = 0; dd < 8; ++dd)
            *(uint4*)&q16[dd * 8] = *(const uint4*)&QKV[(tb + L) * 1536 + h * 64 + dd * 8];
        const int j = cc * 64 + l;
        const bool val = (j <= L);
        float s = -3.0e38f;
        if (val) {
            s = 0.f;
            const u16* kp = &QKV[(tb + j) * 1536 + 512 + h * 64];
            #pragma unroll
            for (int dd = 0; dd < 8; ++dd) {
                uint4 kk = *(const uint4*)&kp[dd * 8];
                const u16* ke = (const u16*)&kk;
                #pragma unroll
                for (int e = 0; e < 8; ++e)
                    s += bf2f(q16[dd * 8 + e]) * bf2f(ke[e]);
            }
            s *= 0.125f;
        }
        float mx = s;
        #pragma unroll
        for (int d = 1; d < 64; d <<= 1) mx = fmaxf(mx, __shfl_xor(mx, d, 64));
        const float p = val ? __expf(s - mx) : 0.f;
        float ps = p;
        #pragma unroll
        for (int d = 1; d < 64; d <<= 1) ps += __shfl_xor(ps, d, 64);
        pP[w * 64 + l] = p;
        __builtin_amdgcn_wave_barrier();
        if (cc * 64 <= L) {
            float oacc = 0.f;
            #pragma unroll 4
            for (int jj = 0; jj < 64; ++jj) {
                const int key = cc * 64 + jj;
                const int rr = (key <= L) ? key : L;   // p==0 there anyway
                oacc += pP[w * 64 + jj] * bf2f(QKV[(tb + rr) * 1536 + 1024 + h * 64 + l]);
            }
            const int pidx = (b * 8 + h) * 32 + cc;
            PBo[(size_t)pidx * 64 + l] = oacc;
            if (l == 0) { PBm[pidx] = mx; PBl[pidx] = ps; }
        }
        return;
    }

    // ---- Phase A ----
    const int i0 = blockIdx.x * 64;
    if (i0 > L) return;  // dead q-tile (pad rows stay stale, finite)

    // Q fragments direct from global (16B aligned)
    bf16x8 qa0, qa1;
    {
        const int qrow = i0 + 16 * w + (l & 15);
        const u16* qp = &QKV[(tb + qrow) * 1536 + h * 64];
        qa0 = *(const bf16x8*)(qp + 8 * (l >> 4));
        qa1 = *(const bf16x8*)(qp + 32 + 8 * (l >> 4));
    }
    const int g0 = (l >> 4) ^ (l & 7);          // swizzled granule, half 0
    const int g1 = ((l >> 4) + 4) ^ (l & 7);    // half 1

    float m_r[4] = {-1e30f, -1e30f, -1e30f, -1e30f};
    float l_r[4] = {0.f, 0.f, 0.f, 0.f};
    f32x4 acc_o[4] = {};
    const int klo = (i0 >= 128) ? (i0 - 64) : 0;
    int khi = (L < klo) ? klo : min(i0 + 63, L);

    for (int j0 = klo; j0 <= khi; j0 += 64) {
        __syncthreads();
        {
            // K: linear LDS dest + inverse-swizzled global source
            const int krow0 = 8 * w + (l >> 3);
            const int kswz = ((l & 7) ^ (l >> 3)) << 3;
            #pragma unroll
            for (int q = 0; q < 2; ++q) {
                const int row = krow0 + 32 * q;
                g2lds16(&QKV[(tb + j0 + row) * 1536 + 512 + h * 64 + kswz],
                        &Ks[(8 * w + 32 * q) * 64]);
            }
            // V: transpose-scatter with swizzle
            const int vr = tid >> 3, c8 = (tid & 7) * 8;
            #pragma unroll
            for (int q = 0; q < 2; ++q) {
                const int row = vr + 32 * q;   // key
                uint4 vv = *(const uint4*)&QKV[(tb + j0 + row) * 1536 + 1024 + h * 64 + c8];
                const u16* vs = (const u16*)&vv;
                #pragma unroll
                for (int e = 0; e < 8; ++e) {
                    const int d = c8 + e;
                    Vt[d * 64 + (((row >> 3) ^ e) << 3) + (row & 7)] = vs[e];
                }
            }
        }
        __syncthreads();
        f32x4 s[4];
        #pragma unroll
        for (int f = 0; f < 4; ++f) {
            f32x4 z = {0.f, 0.f, 0.f, 0.f};
            const int rowk = (f * 16 + (l & 15)) * 64;
            bf16x8 kb0 = *(const bf16x8*)&Ks[rowk + g0 * 8];
            bf16x8 kb1 = *(const bf16x8*)&Ks[rowk + g1 * 8];
            z = MFMA16(qa0, kb0, z);
            z = MFMA16(qa1, kb1, z);
            s[f] = z;
        }
        float pm[4];
        #pragma unroll
        for (int r = 0; r < 4; ++r) {
            const int i_r = i0 + 16 * w + (l >> 4) * 4 + r;
            float mx = -__builtin_inff();
            #pragma unroll
            for (int f = 0; f < 4; ++f) {
                const int j = j0 + f * 16 + (l & 15);
                float sv = s[f][r] * 0.125f;
                const bool ok = (i_r >= L) ? (j == klo)
                              : (j <= i_r && (i_r <= 64 || j >= i_r - 64));
                sv = ok ? sv : -__builtin_inff();
                s[f][r] = sv;
                mx = fmaxf(mx, sv);
            }
            pm[r] = mx;
        }
        #pragma unroll
        for (int d = 1; d < 16; d <<= 1)
            #pragma unroll
            for (int r = 0; r < 4; ++r) pm[r] = fmaxf(pm[r], __shfl_xor(pm[r], d, 64));
        float sc[4];
        #pragma unroll
        for (int r = 0; r < 4; ++r) {
            const float mn = fmaxf(m_r[r], fmaxf(pm[r], -1e30f));
            sc[r] = __expf(m_r[r] - mn);
            m_r[r] = mn;
            l_r[r] *= sc[r];
        }
        #pragma unroll
        for (int f = 0; f < 4; ++f)
            #pragma unroll
            for (int r = 0; r < 4; ++r) acc_o[f][r] *= sc[r];
        float ps[4] = {0.f, 0.f, 0.f, 0.f};
        #pragma unroll
        for (int f = 0; f < 4; ++f)
            #pragma unroll
            for (int r = 0; r < 4; ++r) {
                const float p = __expf(s[f][r] - m_r[r]);
                s[f][r] = p;
                ps[r] += p;
            }
        #pragma unroll
        for (int d = 1; d < 16; d <<= 1)
            #pragma unroll
            for (int r = 0; r < 4; ++r) ps[r] += __shfl_xor(ps[r], d, 64);
        #pragma unroll
        for (int r = 0; r < 4; ++r) l_r[r] += ps[r];
        // P -> LDS (swizzled scatter), then A-fragment reads (2-way)
        {
            const int cg = ((l >> 3) & 1);
            #pragma unroll
            for (int f = 0; f < 4; ++f)
                #pragma unroll
                for (int r = 0; r < 4; ++r) {
                    const int prow = (l >> 4) * 4 + r;
                    Ps[w][prow * 64 + (((f * 2 + cg) ^ (prow & 7)) << 3) + (l & 7)] =
                        f2bf(s[f][r]);
                }
        }
        bf16x8 pa0 = *(const bf16x8*)&Ps[w][(l & 15) * 64 + g0 * 8];
        bf16x8 pa1 = *(const bf16x8*)&Ps[w][(l & 15) * 64 + g1 * 8];
        #pragma unroll
        for (int f = 0; f < 4; ++f) {
            const int dv = (f * 16 + (l & 15)) * 64;
            bf16x8 vb0 = *(const bf16x8*)&Vt[dv + g0 * 8];
            bf16x8 vb1 = *(const bf16x8*)&Vt[dv + g1 * 8];
            acc_o[f] = MFMA16(pa0, vb0, acc_o[f]);
            acc_o[f] = MFMA16(pa1, vb1, acc_o[f]);
        }
    }
    #pragma unroll
    for (int r = 0; r < 4; ++r) {
        const float inv = 1.f / l_r[r];
        const int row = i0 + 16 * w + (l >> 4) * 4 + r;
        if (row != L) {
            #pragma unroll
            for (int f = 0; f < 4; ++f)
                CTX[(tb + row) * 512 + h * 64 + f * 16 + (l & 15)] = f2bf(acc_o[f][r] * inv);
        }
    }
}

// Merge phase-B partials -> CTX row L. grid (8 heads, 16 batches), 64 thr.
__global__ void attn_merge(const float* __restrict__ PBm, const float* __restrict__ PBl,
                           const float* __restrict__ PBo, u16* __restrict__ CTX,
                           const int* __restrict__ obs)
{
    const int h = blockIdx.x, b = blockIdx.y, l = threadIdx.x;
    const int L = obs[b];
    const int nc = (L >> 6) + 1;
    const int base = (b * 8 + h) * 32;
    float m = -3.0e38f;
    for (int c = 0; c < nc; ++c) m = fmaxf(m, PBm[base + c]);
    float lt = 0.f, ot = 0.f;
    for (int c = 0; c < nc; ++c) {
        const float sc = __expf(PBm[base + c] - m);
        lt += sc * PBl[base + c];
        ot += sc * PBo[(size_t)(base + c) * 64 + l];
    }
    CTX[((size_t)b * 2048 + L) * 512 + h * 64 + l] = f2bf(ot / lt);
}

// ---------------------------------------------------------------------------
__global__ __launch_bounds__(256) void ln_kernel(
    const float* __restrict__ Y, const float* __restrict__ gw,
    const float* __restrict__ bw, float* __restrict__ X, u16* __restrict__ Xb,
    const int* __restrict__ obs)
{
    const int tok0 = blockIdx.x * 4;
    if ((tok0 & 2047) > obs[tok0 >> 11]) return;
    const int tok = tok0 + (threadIdx.x >> 6);
    const int l = threadIdx.x & 63;
    const float* y = &Y[(size_t)tok * 512 + l * 8];
    f32x4 v0 = *(const f32x4*)y;
    f32x4 v1 = *(const f32x4*)(y + 4);
    float s = 0.f, sq = 0.f;
    #pragma unroll
    for (int e = 0; e < 4; ++e) {
        s += v0[e] + v1[e];
        sq += v0[e] * v0[e] + v1[e] * v1[e];
    }
    #pragma unroll
    for (int d = 1; d < 64; d <<= 1) {
        s += __shfl_xor(s, d, 64);
        sq += __shfl_xor(sq, d, 64);
    }
    const float mean = s * (1.f / 512.f);
    const float var = sq * (1.f / 512.f) - mean * mean;
    const float rstd = rsqrtf(var + 1e-5f);
    f32x4 o0, o1;
    union { u16 us[8]; uint4 u4; } pk;
    #pragma unroll
    for (int e = 0; e < 8; ++e) {
        const int d = l * 8 + e;
        const float xv = (e < 4) ? v0[e] : v1[e - 4];
        const float ov = (xv - mean) * rstd * gw[d] + bw[d];
        if (e < 4) o0[e] = ov; else o1[e - 4] = ov;
        pk.us[e] = f2bf(ov);
    }
    float* xo = &X[(size_t)tok * 512 + l * 8];
    *(f32x4*)xo = o0;
    *(f32x4*)(xo + 4) = o1;
    *(uint4*)&Xb[(size_t)tok * 512 + l * 8] = pk.u4;
}

__global__ void cast_bf16_kernel(const float* __restrict__ in, u16* __restrict__ out, int n) {
    const int i = (blockIdx.x * 256 + threadIdx.x) * 4;
    if (i + 3 < n) {
        f32x4 v = *(const f32x4*)&in[i];
        union { u16 us[4]; uint2 u2; } pk;
        #pragma unroll
        for (int e = 0; e < 4; ++e) pk.us[e] = f2bf(v[e]);
        *(uint2*)&out[i] = pk.u2;
    }
}

__global__ void transpose_cast(const float* __restrict__ W, u16* __restrict__ WT, int K, int N) {
    __shared__ float t[32][33];
    const int n0 = blockIdx.x * 32, k0 = blockIdx.y * 32;
    const int tx = threadIdx.x, ty = threadIdx.y;
    #pragma unroll
    for (int r = 0; r < 32; r += 8)
        t[ty + r][tx] = W[(size_t)(k0 + ty + r) * N + n0 + tx];
    __syncthreads();
    #pragma unroll
    for (int r = 0; r < 32; r += 8)
        WT[(size_t)(n0 + ty + r) * K + k0 + tx] = f2bf(t[tx][ty + r]);
}

__global__ void transpose_layer(
    const float* __restrict__ wq, const float* __restrict__ wo_,
    const float* __restrict__ wf1, const float* __restrict__ wf2,
    u16* __restrict__ dq, u16* __restrict__ dok,
    u16* __restrict__ df1, u16* __restrict__ df2)
{
    __shared__ float t[32][33];
    int id = blockIdx.x;
    const float* W; u16* D; int K, N;
    if (id < 768)       { W = wq;  D = dq;  K = 512;  N = 1536; }
    else if (id < 1024) { W = wo_; D = dok; K = 512;  N = 512;  id -= 768; }
    else if (id < 2048) { W = wf1; D = df1; K = 512;  N = 2048; id -= 1024; }
    else                { W = wf2; D = df2; K = 2048; N = 512;  id -= 2048; }
    const int nx = N >> 5;
    const int n0 = (id % nx) * 32, k0 = (id / nx) * 32;
    const int tx = threadIdx.x, ty = threadIdx.y;
    #pragma unroll
    for (int r = 0; r < 32; r += 8)
        t[ty + r][tx] = W[(size_t)(k0 + ty + r) * N + n0 + tx];
    __syncthreads();
    #pragma unroll
    for (int r = 0; r < 32; r += 8)
        D[(size_t)(n0 + ty + r) * K + k0 + tx] = f2bf(t[tx][ty + r]);
}

__global__ void agg_partial(const float* __restrict__ X, float* __restrict__ part,
                            const int* __restrict__ obs) {
    const int b = blockIdx.y, c = blockIdx.x, d = threadIdx.x;
    const int L = obs[b];
    float s = 0.f;
    const int t0 = c * 128;
    int tend = t0 + 128;
    if (tend > L + 1) tend = L + 1;
    for (int t = t0; t < tend; ++t) s += X[((size_t)b * 2048 + t) * 512 + d];
    part[((size_t)b * 16 + c) * 512 + d] = s;
}

__global__ void agg_final(const float* __restrict__ part, float* __restrict__ out,
                          const int* __restrict__ obs) {
    const int b = blockIdx.x, d = threadIdx.x;
    float s = 0.f;
    #pragma unroll
    for (int c = 0; c < 16; ++c) s += part[((size_t)b * 16 + c) * 512 + d];
    out[b * 512 + d] = s / (float)(obs[b] + 1);
}

// ---------------------------------------------------------------------------
// Workspace ~210 MB (round-4 ran the >=215MB branch successfully, so safe):
//   U 100.7 | Xb 32 | X 64 | PE 4 | PB ~1.05 | part 0.5 | weights 6.5 MB
// ---------------------------------------------------------------------------
extern "C" void kernel_launch(void* const* d_in, const int* in_sizes, int n_in,
                              void* d_out, int out_size, void* d_ws, size_t ws_size,
                              hipStream_t stream)
{
    const int M = 32768;        // B*T
    const int FCH = 16384;      // FF chunk rows
    const float* traj = (const float*)d_in[0];
    const int* obs = (const int*)d_in[1];
    const float* w_in = (const float*)d_in[2];
    const float* b_in = (const float*)d_in[3];

    char* base = (char*)d_ws;
    size_t off = 0;
    auto carve = [&](size_t bytes) -> void* {
        void* p = base + off;
        off += (bytes + 255) & ~(size_t)255;
        return p;
    };
    u16* U     = (u16*)carve((size_t)M * 1536 * 2);
    u16* Xb    = (u16*)carve((size_t)M * 512 * 2);
    float* X   = (float*)carve((size_t)M * 512 * 4);
    float* PE  = (float*)carve((size_t)2048 * 512 * 4);
    float* PBm = (float*)carve((size_t)16 * 8 * 32 * 4);
    float* PBl = (float*)carve((size_t)16 * 8 * 32 * 4);
    float* PBo = (float*)carve((size_t)16 * 8 * 32 * 64 * 4);
    float* part = (float*)carve((size_t)16 * 16 * 512 * 4);
    u16* wTin  = (u16*)carve((size_t)512 * 512 * 2);
    u16* wqkv  = (u16*)carve((size_t)1536 * 512 * 2);
    u16* wo    = (u16*)carve((size_t)512 * 512 * 2);
    u16* wff1  = (u16*)carve((size_t)2048 * 512 * 2);
    u16* wff2  = (u16*)carve((size_t)512 * 2048 * 2);

    dim3 tb32(32, 8);
    pe_kernel<<<2048, 256, 0, stream>>>(PE);
    transpose_cast<<<dim3(16, 16), tb32, 0, stream>>>(w_in, wTin, 512, 512);

    cast_bf16_kernel<<<(M * 512) / 1024, 256, 0, stream>>>(traj, U, M * 512);
    gemm_bf16<0><<<dim3(4, M / 128), 256, 0, stream>>>(
        U, wTin, b_in, X, Xb, PE, obs, M, 512, 512);

    for (int lyr = 0; lyr < 4; ++lyr) {
        const int bi = 4 + 12 * lyr;
        transpose_layer<<<3072, tb32, 0, stream>>>(
            (const float*)d_in[bi + 0], (const float*)d_in[bi + 2],
            (const float*)d_in[bi + 4], (const float*)d_in[bi + 6],
            wqkv, wo, wff1, wff2);
        const float* b_qkv = (const float*)d_in[bi + 1];
        const float* b_o   = (const float*)d_in[bi + 3];
        const float* b_ff1 = (const float*)d_in[bi + 5];
        const float* b_ff2 = (const float*)d_in[bi + 7];
        const float* ln1g  = (const float*)d_in[bi + 8];
        const float* ln1b  = (const float*)d_in[bi + 9];
        const float* ln2g  = (const float*)d_in[bi + 10];
        const float* ln2b  = (const float*)d_in[bi + 11];

        gemm_bf16<1><<<dim3(12, M / 128), 256, 0, stream>>>(
            Xb, wqkv, b_qkv, nullptr, U, nullptr, obs, M, 1536, 512);
        attn_kernel<<<dim3(40, 8, 16), 256, 0, stream>>>(U, Xb, obs, PBm, PBl, PBo);
        attn_merge<<<dim3(8, 16), 64, 0, stream>>>(PBm, PBl, PBo, Xb, obs);
        gemm_bf16<2><<<dim3(4, M / 128), 256, 0, stream>>>(
            Xb, wo, b_o, X, nullptr, X, obs, M, 512, 512);
        ln_kernel<<<M / 4, 256, 0, stream>>>(X, ln1g, ln1b, X, Xb, obs);
        for (int c = 0; c < 2; ++c) {
            gemm_bf16<3><<<dim3(16, FCH / 128), 256, 0, stream>>>(
                Xb + (size_t)c * FCH * 512, wff1, b_ff1, nullptr, U, nullptr,
                obs + c * 8, FCH, 2048, 512);
            gemm_bf16<2><<<dim3(4, FCH / 128), 256, 0, stream>>>(
                U, wff2, b_ff2, X + (size_t)c * FCH * 512, nullptr,
                X + (size_t)c * FCH * 512, obs + c * 8, FCH, 512, 2048);
        }
        ln_kernel<<<M / 4, 256, 0, stream>>>(X, ln2g, ln2b, X, Xb, obs);
    }

    agg_partial<<<dim3(16, 16), 512, 0, stream>>>(X, part, obs);
    agg_final<<<16, 512, 0, stream>>>(part, (float*)d_out, obs);
}

// Round 7
// 1360.068 us; speedup vs baseline: 2.8906x; 1.1982x over previous
//
#include <hip/hip_runtime.h>

typedef unsigned short u16;
typedef unsigned int u32;
typedef __bf16 bf16x8 __attribute__((ext_vector_type(8)));
typedef float f32x4 __attribute__((ext_vector_type(4)));

#define MFMA16(a, b, c) __builtin_amdgcn_mfma_f32_16x16x32_bf16((a), (b), (c), 0, 0, 0)

__device__ __forceinline__ u16 f2bf(float x) {
    union { float f; u32 u; } v; v.f = x;
    u32 r = v.u + 0x7fffu + ((v.u >> 16) & 1u);
    return (u16)(r >> 16);
}
__device__ __forceinline__ float bf2f(u16 x) {
    union { u32 u; float f; } v; v.u = ((u32)x) << 16; return v.f;
}

typedef const __attribute__((address_space(1))) u32* gas1_t;
typedef __attribute__((address_space(3))) u32* las3_t;
__device__ __forceinline__ void g2lds16(const void* g, void* l) {
    __builtin_amdgcn_global_load_lds((gas1_t)g, (las3_t)l, 16, 0, 0);
}

// ---------------------------------------------------------------------------
// GEMM: m97 fragment layout + 2-phase dbuf staging + dead-tile skip +
// BALANCED XCD mapping: xcd(tm) = (tm + batch) & 7 — per-batch rotation so
// the live-prefix (rows <= obs[b]) spreads evenly across XCDs, while all
// tn-tiles of one tm stay consecutive within an XCD (A-panel L2 reuse).
// Bijective inverse (requires gy%16==0, true for all dispatches):
//   xcd=orig&7, loc=orig>>3, tn=loc%gx, j=loc/gx, b=j>>1,
//   tm = 16*b + ((xcd-b)&7) + 8*(j&1).
// ---------------------------------------------------------------------------
template <int MODE>
__global__ __launch_bounds__(256) void gemm_bf16(
    const u16* __restrict__ A, const u16* __restrict__ BT,
    const float* __restrict__ bias, float* __restrict__ outF,
    u16* __restrict__ outB, const float* __restrict__ aux,
    const int* __restrict__ obs,
    int M, int N, int K)
{
    __shared__ u16 As[2][128 * 32];
    __shared__ u16 Bs[2][128 * 32];
    const int tid = threadIdx.x;
    const int w = tid >> 6, l = tid & 63;
    const int gx = gridDim.x, gy = gridDim.y;
    const int orig = blockIdx.y * gx + blockIdx.x;
    int tm, tn;
    if ((gy & 15) == 0) {
        const int xcd = orig & 7;
        const int loc = orig >> 3;
        tn = loc % gx;
        const int j = loc / gx;              // [0, gy/8)
        const int bb = j >> 1;               // batch index
        tm = bb * 16 + ((xcd - bb) & 7) + ((j & 1) << 3);
    } else {
        tm = blockIdx.y; tn = blockIdx.x;
    }
    const int bm = tm * 128, bn = tn * 128;
    if ((bm & 2047) > obs[bm >> 11]) return;   // dead tile (pad rows only)
    const int wr = (w >> 1) * 64, wc = (w & 1) * 64;
    const int larow = l >> 2, lacol = (l & 3) * 8;
    f32x4 acc[4][4] = {};

    const int r0a = 16 * w, r0b = 16 * (w + 4);
    const u16* Ap = &A[(size_t)(bm + larow) * K + lacol];
    const u16* Bp = &BT[(size_t)(bn + larow) * K + lacol];

    {
        g2lds16(Ap + (size_t)r0a * K, &As[0][r0a * 32]);
        g2lds16(Bp + (size_t)r0a * K, &Bs[0][r0a * 32]);
        g2lds16(Ap + (size_t)r0b * K, &As[0][r0b * 32]);
        g2lds16(Bp + (size_t)r0b * K, &Bs[0][r0b * 32]);
    }
    __syncthreads();
    int cur = 0;
    const int nk = K >> 5;
    for (int ki = 0; ki < nk; ++ki) {
        if (ki + 1 < nk) {
            const int kt = (ki + 1) << 5;
            g2lds16(Ap + (size_t)r0a * K + kt, &As[cur ^ 1][r0a * 32]);
            g2lds16(Bp + (size_t)r0a * K + kt, &Bs[cur ^ 1][r0a * 32]);
            g2lds16(Ap + (size_t)r0b * K + kt, &As[cur ^ 1][r0b * 32]);
            g2lds16(Bp + (size_t)r0b * K + kt, &Bs[cur ^ 1][r0b * 32]);
        }
        bf16x8 af[4], bfr[4];
        #pragma unroll
        for (int i = 0; i < 4; ++i)
            af[i] = *(const bf16x8*)&As[cur][(wr + i * 16 + (l & 15)) * 32 + 8 * (l >> 4)];
        #pragma unroll
        for (int j = 0; j < 4; ++j)
            bfr[j] = *(const bf16x8*)&Bs[cur][(wc + j * 16 + (l & 15)) * 32 + 8 * (l >> 4)];
        #pragma unroll
        for (int i = 0; i < 4; ++i)
            #pragma unroll
            for (int j = 0; j < 4; ++j)
                acc[i][j] = MFMA16(af[i], bfr[j], acc[i][j]);
        __syncthreads();
        cur ^= 1;
    }

    const int r0 = bm + wr + (l >> 4) * 4;
    const int c0 = bn + wc + (l & 15);
    #pragma unroll
    for (int i = 0; i < 4; ++i) {
        #pragma unroll
        for (int j = 0; j < 4; ++j) {
            const int col = c0 + j * 16;
            const float bc = bias[col];
            #pragma unroll
            for (int r = 0; r < 4; ++r) {
                const int row = r0 + i * 16 + r;
                const size_t idx = (size_t)row * N + col;
                float val = acc[i][j][r] + bc;
                if constexpr (MODE == 0) {
                    val += aux[(size_t)(row & 2047) * 512 + col];
                    outF[idx] = val;
                    outB[idx] = f2bf(val);
                } else if constexpr (MODE == 1) {
                    outB[idx] = f2bf(val);
                } else if constexpr (MODE == 2) {
                    outF[idx] = val + aux[idx];
                } else {
                    outB[idx] = f2bf(fmaxf(val, 0.f));
                }
            }
        }
    }
}

__global__ void pe_kernel(float* __restrict__ PE) {
    const int idx = blockIdx.x * 256 + threadIdx.x;
    const int t = idx >> 8, p = idx & 255;
    const float fr = expf((float)(2 * p) * -0.017988946039015984f);
    const float arg = (float)t * fr;
    float s, c;
    sincosf(arg, &s, &c);
    float2 v = {s, c};
    *(float2*)&PE[(size_t)t * 512 + 2 * p] = v;
}

// ---------------------------------------------------------------------------
// Flash attention (unchanged from round 6).
// ---------------------------------------------------------------------------
__global__ __launch_bounds__(256) void attn_kernel(
    const u16* __restrict__ QKV, u16* __restrict__ CTX, const int* __restrict__ obs,
    float* __restrict__ PBm, float* __restrict__ PBl, float* __restrict__ PBo)
{
    __shared__ u16 Ks[64 * 64];
    __shared__ u16 Vt[64 * 64];
    __shared__ u16 Ps[4][16 * 64];
    const int b = blockIdx.z, h = blockIdx.y;
    const int L = obs[b];
    const int tid = threadIdx.x, w = tid >> 6, l = tid & 63;
    const size_t tb = (size_t)b * 2048;

    if (blockIdx.x >= 32) {
        const int cbase = (blockIdx.x - 32) * 4;
        if (cbase * 64 > L) return;
        const int cc = cbase + w;
        float* pP = (float*)Ks;
        u16 q16[64];
        #pragma unroll
        for (int dd = 0; dd < 8; ++dd)
            *(uint4*)&q16[dd * 8] = *(const uint4*)&QKV[(tb + L) * 1536 + h * 64 + dd * 8];
        const int j = cc * 64 + l;
        const bool val = (j <= L);
        float s = -3.0e38f;
        if (val) {
            s = 0.f;
            const u16* kp = &QKV[(tb + j) * 1536 + 512 + h * 64];
            #pragma unroll
            for (int dd = 0; dd < 8; ++dd) {
                uint4 kk = *(const uint4*)&kp[dd * 8];
                const u16* ke = (const u16*)&kk;
                #pragma unroll
                for (int e = 0; e < 8; ++e)
                    s += bf2f(q16[dd * 8 + e]) * bf2f(ke[e]);
            }
            s *= 0.125f;
        }
        float mx = s;
        #pragma unroll
        for (int d = 1; d < 64; d <<= 1) mx = fmaxf(mx, __shfl_xor(mx, d, 64));
        const float p = val ? __expf(s - mx) : 0.f;
        float ps = p;
        #pragma unroll
        for (int d = 1; d < 64; d <<= 1) ps += __shfl_xor(ps, d, 64);
        pP[w * 64 + l] = p;
        __builtin_amdgcn_wave_barrier();
        if (cc * 64 <= L) {
            float oacc = 0.f;
            #pragma unroll 4
            for (int jj = 0; jj < 64; ++jj) {
                const int key = cc * 64 + jj;
                const int rr = (key <= L) ? key : L;
                oacc += pP[w * 64 + jj] * bf2f(QKV[(tb + rr) * 1536 + 1024 + h * 64 + l]);
            }
            const int pidx = (b * 8 + h) * 32 + cc;
            PBo[(size_t)pidx * 64 + l] = oacc;
            if (l == 0) { PBm[pidx] = mx; PBl[pidx] = ps; }
        }
        return;
    }

    const int i0 = blockIdx.x * 64;
    if (i0 > L) return;

    bf16x8 qa0, qa1;
    {
        const int qrow = i0 + 16 * w + (l & 15);
        const u16* qp = &QKV[(tb + qrow) * 1536 + h * 64];
        qa0 = *(const bf16x8*)(qp + 8 * (l >> 4));
        qa1 = *(const bf16x8*)(qp + 32 + 8 * (l >> 4));
    }
    const int g0 = (l >> 4) ^ (l & 7);
    const int g1 = ((l >> 4) + 4) ^ (l & 7);

    float m_r[4] = {-1e30f, -1e30f, -1e30f, -1e30f};
    float l_r[4] = {0.f, 0.f, 0.f, 0.f};
    f32x4 acc_o[4] = {};
    const int klo = (i0 >= 128) ? (i0 - 64) : 0;
    int khi = (L < klo) ? klo : min(i0 + 63, L);

    for (int j0 = klo; j0 <= khi; j0 += 64) {
        __syncthreads();
        {
            const int krow0 = 8 * w + (l >> 3);
            const int kswz = ((l & 7) ^ (l >> 3)) << 3;
            #pragma unroll
            for (int q = 0; q < 2; ++q) {
                const int row = krow0 + 32 * q;
                g2lds16(&QKV[(tb + j0 + row) * 1536 + 512 + h * 64 + kswz],
                        &Ks[(8 * w + 32 * q) * 64]);
            }
            const int vr = tid >> 3, c8 = (tid & 7) * 8;
            #pragma unroll
            for (int q = 0; q < 2; ++q) {
                const int row = vr + 32 * q;
                uint4 vv = *(const uint4*)&QKV[(tb + j0 + row) * 1536 + 1024 + h * 64 + c8];
                const u16* vs = (const u16*)&vv;
                #pragma unroll
                for (int e = 0; e < 8; ++e) {
                    const int d = c8 + e;
                    Vt[d * 64 + (((row >> 3) ^ e) << 3) + (row & 7)] = vs[e];
                }
            }
        }
        __syncthreads();
        f32x4 s[4];
        #pragma unroll
        for (int f = 0; f < 4; ++f) {
            f32x4 z = {0.f, 0.f, 0.f, 0.f};
            const int rowk = (f * 16 + (l & 15)) * 64;
            bf16x8 kb0 = *(const bf16x8*)&Ks[rowk + g0 * 8];
            bf16x8 kb1 = *(const bf16x8*)&Ks[rowk + g1 * 8];
            z = MFMA16(qa0, kb0, z);
            z = MFMA16(qa1, kb1, z);
            s[f] = z;
        }
        float pm[4];
        #pragma unroll
        for (int r = 0; r < 4; ++r) {
            const int i_r = i0 + 16 * w + (l >> 4) * 4 + r;
            float mx = -__builtin_inff();
            #pragma unroll
            for (int f = 0; f < 4; ++f) {
                const int j = j0 + f * 16 + (l & 15);
                float sv = s[f][r] * 0.125f;
                const bool ok = (i_r >= L) ? (j == klo)
                              : (j <= i_r && (i_r <= 64 || j >= i_r - 64));
                sv = ok ? sv : -__builtin_inff();
                s[f][r] = sv;
                mx = fmaxf(mx, sv);
            }
            pm[r] = mx;
        }
        #pragma unroll
        for (int d = 1; d < 16; d <<= 1)
            #pragma unroll
            for (int r = 0; r < 4; ++r) pm[r] = fmaxf(pm[r], __shfl_xor(pm[r], d, 64));
        float sc[4];
        #pragma unroll
        for (int r = 0; r < 4; ++r) {
            const float mn = fmaxf(m_r[r], fmaxf(pm[r], -1e30f));
            sc[r] = __expf(m_r[r] - mn);
            m_r[r] = mn;
            l_r[r] *= sc[r];
        }
        #pragma unroll
        for (int f = 0; f < 4; ++f)
            #pragma unroll
            for (int r = 0; r < 4; ++r) acc_o[f][r] *= sc[r];
        float ps[4] = {0.f, 0.f, 0.f, 0.f};
        #pragma unroll
        for (int f = 0; f < 4; ++f)
            #pragma unroll
            for (int r = 0; r < 4; ++r) {
                const float p = __expf(s[f][r] - m_r[r]);
                s[f][r] = p;
                ps[r] += p;
            }
        #pragma unroll
        for (int d = 1; d < 16; d <<= 1)
            #pragma unroll
            for (int r = 0; r < 4; ++r) ps[r] += __shfl_xor(ps[r], d, 64);
        #pragma unroll
        for (int r = 0; r < 4; ++r) l_r[r] += ps[r];
        {
            const int cg = ((l >> 3) & 1);
            #pragma unroll
            for (int f = 0; f < 4; ++f)
                #pragma unroll
                for (int r = 0; r < 4; ++r) {
                    const int prow = (l >> 4) * 4 + r;
                    Ps[w][prow * 64 + (((f * 2 + cg) ^ (prow & 7)) << 3) + (l & 7)] =
                        f2bf(s[f][r]);
                }
        }
        bf16x8 pa0 = *(const bf16x8*)&Ps[w][(l & 15) * 64 + g0 * 8];
        bf16x8 pa1 = *(const bf16x8*)&Ps[w][(l & 15) * 64 + g1 * 8];
        #pragma unroll
        for (int f = 0; f < 4; ++f) {
            const int dv = (f * 16 + (l & 15)) * 64;
            bf16x8 vb0 = *(const bf16x8*)&Vt[dv + g0 * 8];
            bf16x8 vb1 = *(const bf16x8*)&Vt[dv + g1 * 8];
            acc_o[f] = MFMA16(pa0, vb0, acc_o[f]);
            acc_o[f] = MFMA16(pa1, vb1, acc_o[f]);
        }
    }
    #pragma unroll
    for (int r = 0; r < 4; ++r) {
        const float inv = 1.f / l_r[r];
        const int row = i0 + 16 * w + (l >> 4) * 4 + r;
        if (row != L) {
            #pragma unroll
            for (int f = 0; f < 4; ++f)
                CTX[(tb + row) * 512 + h * 64 + f * 16 + (l & 15)] = f2bf(acc_o[f][r] * inv);
        }
    }
}

__global__ void attn_merge(const float* __restrict__ PBm, const float* __restrict__ PBl,
                           const float* __restrict__ PBo, u16* __restrict__ CTX,
                           const int* __restrict__ obs)
{
    const int h = blockIdx.x, b = blockIdx.y, l = threadIdx.x;
    const int L = obs[b];
    const int nc = (L >> 6) + 1;
    const int base = (b * 8 + h) * 32;
    float m = -3.0e38f;
    for (int c = 0; c < nc; ++c) m = fmaxf(m, PBm[base + c]);
    float lt = 0.f, ot = 0.f;
    for (int c = 0; c < nc; ++c) {
        const float sc = __expf(PBm[base + c] - m);
        lt += sc * PBl[base + c];
        ot += sc * PBo[(size_t)(base + c) * 64 + l];
    }
    CTX[((size_t)b * 2048 + L) * 512 + h * 64 + l] = f2bf(ot / lt);
}

// ---------------------------------------------------------------------------
__global__ __launch_bounds__(256) void ln_kernel(
    const float* __restrict__ Y, const float* __restrict__ gw,
    const float* __restrict__ bw, float* __restrict__ X, u16* __restrict__ Xb,
    const int* __restrict__ obs)
{
    const int tok0 = blockIdx.x * 4;
    if ((tok0 & 2047) > obs[tok0 >> 11]) return;
    const int tok = tok0 + (threadIdx.x >> 6);
    const int l = threadIdx.x & 63;
    const float* y = &Y[(size_t)tok * 512 + l * 8];
    f32x4 v0 = *(const f32x4*)y;
    f32x4 v1 = *(const f32x4*)(y + 4);
    float s = 0.f, sq = 0.f;
    #pragma unroll
    for (int e = 0; e < 4; ++e) {
        s += v0[e] + v1[e];
        sq += v0[e] * v0[e] + v1[e] * v1[e];
    }
    #pragma unroll
    for (int d = 1; d < 64; d <<= 1) {
        s += __shfl_xor(s, d, 64);
        sq += __shfl_xor(sq, d, 64);
    }
    const float mean = s * (1.f / 512.f);
    const float var = sq * (1.f / 512.f) - mean * mean;
    const float rstd = rsqrtf(var + 1e-5f);
    f32x4 o0, o1;
    union { u16 us[8]; uint4 u4; } pk;
    #pragma unroll
    for (int e = 0; e < 8; ++e) {
        const int d = l * 8 + e;
        const float xv = (e < 4) ? v0[e] : v1[e - 4];
        const float ov = (xv - mean) * rstd * gw[d] + bw[d];
        if (e < 4) o0[e] = ov; else o1[e - 4] = ov;
        pk.us[e] = f2bf(ov);
    }
    float* xo = &X[(size_t)tok * 512 + l * 8];
    *(f32x4*)xo = o0;
    *(f32x4*)(xo + 4) = o1;
    *(uint4*)&Xb[(size_t)tok * 512 + l * 8] = pk.u4;
}

__global__ void cast_bf16_kernel(const float* __restrict__ in, u16* __restrict__ out, int n) {
    const int i = (blockIdx.x * 256 + threadIdx.x) * 4;
    if (i + 3 < n) {
        f32x4 v = *(const f32x4*)&in[i];
        union { u16 us[4]; uint2 u2; } pk;
        #pragma unroll
        for (int e = 0; e < 4; ++e) pk.us[e] = f2bf(v[e]);
        *(uint2*)&out[i] = pk.u2;
    }
}

__global__ void transpose_cast(const float* __restrict__ W, u16* __restrict__ WT, int K, int N) {
    __shared__ float t[32][33];
    const int n0 = blockIdx.x * 32, k0 = blockIdx.y * 32;
    const int tx = threadIdx.x, ty = threadIdx.y;
    #pragma unroll
    for (int r = 0; r < 32; r += 8)
        t[ty + r][tx] = W[(size_t)(k0 + ty + r) * N + n0 + tx];
    __syncthreads();
    #pragma unroll
    for (int r = 0; r < 32; r += 8)
        WT[(size_t)(n0 + ty + r) * K + k0 + tx] = f2bf(t[tx][ty + r]);
}

// All 16 per-layer weight matrices transposed in ONE launch (4 x 3072 blocks).
struct WPack { const float* src[16]; u16* dst[16]; };
__global__ void transpose_all(WPack p) {
    __shared__ float t[32][33];
    int id = blockIdx.x;
    const int lyr = id / 3072;
    id -= lyr * 3072;
    int wi, K, N;
    if (id < 768)       { wi = 0; K = 512;  N = 1536; }
    else if (id < 1024) { wi = 1; K = 512;  N = 512;  id -= 768; }
    else if (id < 2048) { wi = 2; K = 512;  N = 2048; id -= 1024; }
    else                { wi = 3; K = 2048; N = 512;  id -= 2048; }
    const float* W = p.src[lyr * 4 + wi];
    u16* D = p.dst[lyr * 4 + wi];
    const int nx = N >> 5;
    const int n0 = (id % nx) * 32, k0 = (id / nx) * 32;
    const int tx = threadIdx.x, ty = threadIdx.y;
    #pragma unroll
    for (int r = 0; r < 32; r += 8)
        t[ty + r][tx] = W[(size_t)(k0 + ty + r) * N + n0 + tx];
    __syncthreads();
    #pragma unroll
    for (int r = 0; r < 32; r += 8)
        D[(size_t)(n0 + ty + r) * K + k0 + tx] = f2bf(t[tx][ty + r]);
}

__global__ void agg_partial(const float* __restrict__ X, float* __restrict__ part,
                            const int* __restrict__ obs) {
    const int b = blockIdx.y, c = blockIdx.x, d = threadIdx.x;
    const int L = obs[b];
    float s = 0.f;
    const int t0 = c * 128;
    int tend = t0 + 128;
    if (tend > L + 1) tend = L + 1;
    for (int t = t0; t < tend; ++t) s += X[((size_t)b * 2048 + t) * 512 + d];
    part[((size_t)b * 16 + c) * 512 + d] = s;
}

__global__ void agg_final(const float* __restrict__ part, float* __restrict__ out,
                          const int* __restrict__ obs) {
    const int b = blockIdx.x, d = threadIdx.x;
    float s = 0.f;
    #pragma unroll
    for (int c = 0; c < 16; ++c) s += part[((size_t)b * 16 + c) * 512 + d];
    out[b * 512 + d] = s / (float)(obs[b] + 1);
}

// ---------------------------------------------------------------------------
// Workspace ~233 MB (<= 237 MB proven in round 4):
//   U 100.7 | Xb 32 | X 64 | PE 4 | PB 1.1 | part 0.5 | weights 25.7 MB
// ---------------------------------------------------------------------------
extern "C" void kernel_launch(void* const* d_in, const int* in_sizes, int n_in,
                              void* d_out, int out_size, void* d_ws, size_t ws_size,
                              hipStream_t stream)
{
    const int M = 32768;        // B*T
    const int FCH = 16384;      // FF chunk rows
    const float* traj = (const float*)d_in[0];
    const int* obs = (const int*)d_in[1];
    const float* w_in = (const float*)d_in[2];
    const float* b_in = (const float*)d_in[3];

    char* base = (char*)d_ws;
    size_t off = 0;
    auto carve = [&](size_t bytes) -> void* {
        void* p = base + off;
        off += (bytes + 255) & ~(size_t)255;
        return p;
    };
    u16* U     = (u16*)carve((size_t)M * 1536 * 2);
    u16* Xb    = (u16*)carve((size_t)M * 512 * 2);
    float* X   = (float*)carve((size_t)M * 512 * 4);
    float* PE  = (float*)carve((size_t)2048 * 512 * 4);
    float* PBm = (float*)carve((size_t)16 * 8 * 32 * 4);
    float* PBl = (float*)carve((size_t)16 * 8 * 32 * 4);
    float* PBo = (float*)carve((size_t)16 * 8 * 32 * 64 * 4);
    float* part = (float*)carve((size_t)16 * 16 * 512 * 4);
    u16* wTin  = (u16*)carve((size_t)512 * 512 * 2);
    u16 *wqkv[4], *wo[4], *wff1[4], *wff2[4];
    for (int l = 0; l < 4; ++l) {
        wqkv[l] = (u16*)carve((size_t)1536 * 512 * 2);
        wo[l]   = (u16*)carve((size_t)512 * 512 * 2);
        wff1[l] = (u16*)carve((size_t)2048 * 512 * 2);
        wff2[l] = (u16*)carve((size_t)512 * 2048 * 2);
    }

    dim3 tb32(32, 8);
    pe_kernel<<<2048, 256, 0, stream>>>(PE);
    transpose_cast<<<dim3(16, 16), tb32, 0, stream>>>(w_in, wTin, 512, 512);
    {
        WPack p;
        for (int l = 0; l < 4; ++l) {
            const int bi = 4 + 12 * l;
            p.src[l * 4 + 0] = (const float*)d_in[bi + 0];
            p.src[l * 4 + 1] = (const float*)d_in[bi + 2];
            p.src[l * 4 + 2] = (const float*)d_in[bi + 4];
            p.src[l * 4 + 3] = (const float*)d_in[bi + 6];
            p.dst[l * 4 + 0] = wqkv[l];
            p.dst[l * 4 + 1] = wo[l];
            p.dst[l * 4 + 2] = wff1[l];
            p.dst[l * 4 + 3] = wff2[l];
        }
        transpose_all<<<12288, tb32, 0, stream>>>(p);
    }

    cast_bf16_kernel<<<(M * 512) / 1024, 256, 0, stream>>>(traj, U, M * 512);
    gemm_bf16<0><<<dim3(4, M / 128), 256, 0, stream>>>(
        U, wTin, b_in, X, Xb, PE, obs, M, 512, 512);

    for (int lyr = 0; lyr < 4; ++lyr) {
        const int bi = 4 + 12 * lyr;
        const float* b_qkv = (const float*)d_in[bi + 1];
        const float* b_o   = (const float*)d_in[bi + 3];
        const float* b_ff1 = (const float*)d_in[bi + 5];
        const float* b_ff2 = (const float*)d_in[bi + 7];
        const float* ln1g  = (const float*)d_in[bi + 8];
        const float* ln1b  = (const float*)d_in[bi + 9];
        const float* ln2g  = (const float*)d_in[bi + 10];
        const float* ln2b  = (const float*)d_in[bi + 11];

        gemm_bf16<1><<<dim3(12, M / 128), 256, 0, stream>>>(
            Xb, wqkv[lyr], b_qkv, nullptr, U, nullptr, obs, M, 1536, 512);
        attn_kernel<<<dim3(40, 8, 16), 256, 0, stream>>>(U, Xb, obs, PBm, PBl, PBo);
        attn_merge<<<dim3(8, 16), 64, 0, stream>>>(PBm, PBl, PBo, Xb, obs);
        gemm_bf16<2><<<dim3(4, M / 128), 256, 0, stream>>>(
            Xb, wo[lyr], b_o, X, nullptr, X, obs, M, 512, 512);
        ln_kernel<<<M / 4, 256, 0, stream>>>(X, ln1g, ln1b, X, Xb, obs);
        for (int c = 0; c < 2; ++c) {
            gemm_bf16<3><<<dim3(16, FCH / 128), 256, 0, stream>>>(
                Xb + (size_t)c * FCH * 512, wff1[lyr], b_ff1, nullptr, U, nullptr,
                obs + c * 8, FCH, 2048, 512);
            gemm_bf16<2><<<dim3(4, FCH / 128), 256, 0, stream>>>(
                U, wff2[lyr], b_ff2, X + (size_t)c * FCH * 512, nullptr,
                X + (size_t)c * FCH * 512, obs + c * 8, FCH, 512, 2048);
        }
        ln_kernel<<<M / 4, 256, 0, stream>>>(X, ln2g, ln2b, X, Xb, obs);
    }

    agg_partial<<<dim3(16, 16), 512, 0, stream>>>(X, part, obs);
    agg_final<<<16, 512, 0, stream>>>(part, (float*)d_out, obs);
}

// Round 8
// 1266.581 us; speedup vs baseline: 3.1040x; 1.0738x over previous
//
#include <hip/hip_runtime.h>

typedef unsigned short u16;
typedef unsigned int u32;
typedef __bf16 bf16x8 __attribute__((ext_vector_type(8)));
typedef float f32x4 __attribute__((ext_vector_type(4)));

#define MFMA16(a, b, c) __builtin_amdgcn_mfma_f32_16x16x32_bf16((a), (b), (c), 0, 0, 0)

__device__ __forceinline__ u16 f2bf(float x) {
    union { float f; u32 u; } v; v.f = x;
    u32 r = v.u + 0x7fffu + ((v.u >> 16) & 1u);
    return (u16)(r >> 16);
}
__device__ __forceinline__ float bf2f(u16 x) {
    union { u32 u; float f; } v; v.u = ((u32)x) << 16; return v.f;
}

typedef const __attribute__((address_space(1))) u32* gas1_t;
typedef __attribute__((address_space(3))) u32* las3_t;
__device__ __forceinline__ void g2lds16(const void* g, void* l) {
    __builtin_amdgcn_global_load_lds((gas1_t)g, (las3_t)l, 16, 0, 0);
}

// ---------------------------------------------------------------------------
// GEMM: m97 fragment layout + 2-phase dbuf staging + dead-tile skip +
// balanced XCD mapping (xcd(tm)=(tm+batch)&7, bijective for gy%16==0).
// BK=32: [128][32] rows = 64B, conflict-free as-is (wide-N GEMMs, 4-5 blk/CU).
// BK=64: [128][64] rows = 128B -> 16-way conflict; fixed by rule-21 both-sides
//   XOR swizzle: inverse-swizzled GLOBAL source -> linear LDS (global_load_lds),
//   swizzled granule on fragment read. For narrow-N GEMMs (2 blk/CU) where
//   halving barrier count is the win.
// MODE 0: += PE table; f32+bf16 out. 1: bf16. 2: +=resid f32. 3: relu bf16.
// ---------------------------------------------------------------------------
template <int MODE, int BK>
__global__ __launch_bounds__(256) void gemm_bf16(
    const u16* __restrict__ A, const u16* __restrict__ BT,
    const float* __restrict__ bias, float* __restrict__ outF,
    u16* __restrict__ outB, const float* __restrict__ aux,
    const int* __restrict__ obs,
    int M, int N, int K)
{
    __shared__ u16 As[2][128 * BK];
    __shared__ u16 Bs[2][128 * BK];
    const int tid = threadIdx.x;
    const int w = tid >> 6, l = tid & 63;
    const int gx = gridDim.x, gy = gridDim.y;
    const int orig = blockIdx.y * gx + blockIdx.x;
    int tm, tn;
    if ((gy & 15) == 0) {
        const int xcd = orig & 7;
        const int loc = orig >> 3;
        tn = loc % gx;
        const int j = loc / gx;
        const int bb = j >> 1;
        tm = bb * 16 + ((xcd - bb) & 7) + ((j & 1) << 3);
    } else {
        tm = blockIdx.y; tn = blockIdx.x;
    }
    const int bm = tm * 128, bn = tn * 128;
    if ((bm & 2047) > obs[bm >> 11]) return;   // dead tile (pad rows only)
    const int wr = (w >> 1) * 64, wc = (w & 1) * 64;
    f32x4 acc[4][4] = {};
    const int lane15 = l & 15, lhi = l >> 4;

    // --- staging setup ---
    const int larow = l >> 2, lacol = (l & 3) * 8;          // BK=32 path
    const int r0a = 16 * w, r0b = 16 * (w + 4);
    const u16* Ap = &A[(size_t)(bm + larow) * K + lacol];
    const u16* Bp = &BT[(size_t)(bn + larow) * K + lacol];
    const int srow = l >> 3;                                 // BK=64 path
    const int scol = ((l & 7) ^ srow) << 3;                  // inverse swizzle

    auto STAGE = [&](int buf, int kt) {
        if constexpr (BK == 32) {
            g2lds16(Ap + (size_t)r0a * K + kt, &As[buf][r0a * 32]);
            g2lds16(Bp + (size_t)r0a * K + kt, &Bs[buf][r0a * 32]);
            g2lds16(Ap + (size_t)r0b * K + kt, &As[buf][r0b * 32]);
            g2lds16(Bp + (size_t)r0b * K + kt, &Bs[buf][r0b * 32]);
        } else {
            #pragma unroll
            for (int q = 0; q < 4; ++q) {
                const int rr = w * 32 + q * 8;
                g2lds16(&A[(size_t)(bm + rr + srow) * K + kt + scol], &As[buf][rr * 64]);
                g2lds16(&BT[(size_t)(bn + rr + srow) * K + kt + scol], &Bs[buf][rr * 64]);
            }
        }
    };

    STAGE(0, 0);
    __syncthreads();
    int cur = 0;
    const int nk = K / BK;
    for (int ki = 0; ki < nk; ++ki) {
        if (ki + 1 < nk) STAGE(cur ^ 1, (ki + 1) * BK);
        if constexpr (BK == 32) {
            bf16x8 af[4], bfr[4];
            #pragma unroll
            for (int i = 0; i < 4; ++i)
                af[i] = *(const bf16x8*)&As[cur][(wr + i * 16 + lane15) * 32 + 8 * lhi];
            #pragma unroll
            for (int j = 0; j < 4; ++j)
                bfr[j] = *(const bf16x8*)&Bs[cur][(wc + j * 16 + lane15) * 32 + 8 * lhi];
            #pragma unroll
            for (int i = 0; i < 4; ++i)
                #pragma unroll
                for (int j = 0; j < 4; ++j)
                    acc[i][j] = MFMA16(af[i], bfr[j], acc[i][j]);
        } else {
            #pragma unroll
            for (int kk = 0; kk < 2; ++kk) {
                const int gsw = ((kk * 4 + lhi) ^ (l & 7)) << 3;  // swizzled read
                bf16x8 af[4], bfr[4];
                #pragma unroll
                for (int i = 0; i < 4; ++i)
                    af[i] = *(const bf16x8*)&As[cur][(wr + i * 16 + lane15) * 64 + gsw];
                #pragma unroll
                for (int j = 0; j < 4; ++j)
                    bfr[j] = *(const bf16x8*)&Bs[cur][(wc + j * 16 + lane15) * 64 + gsw];
                #pragma unroll
                for (int i = 0; i < 4; ++i)
                    #pragma unroll
                    for (int j = 0; j < 4; ++j)
                        acc[i][j] = MFMA16(af[i], bfr[j], acc[i][j]);
            }
        }
        __syncthreads();
        cur ^= 1;
    }

    const int r0 = bm + wr + lhi * 4;
    const int c0 = bn + wc + lane15;
    #pragma unroll
    for (int i = 0; i < 4; ++i) {
        #pragma unroll
        for (int j = 0; j < 4; ++j) {
            const int col = c0 + j * 16;
            const float bc = bias[col];
            #pragma unroll
            for (int r = 0; r < 4; ++r) {
                const int row = r0 + i * 16 + r;
                const size_t idx = (size_t)row * N + col;
                float val = acc[i][j][r] + bc;
                if constexpr (MODE == 0) {
                    val += aux[(size_t)(row & 2047) * 512 + col];
                    outF[idx] = val;
                    outB[idx] = f2bf(val);
                } else if constexpr (MODE == 1) {
                    outB[idx] = f2bf(val);
                } else if constexpr (MODE == 2) {
                    outF[idx] = val + aux[idx];
                } else {
                    outB[idx] = f2bf(fmaxf(val, 0.f));
                }
            }
        }
    }
}

__global__ void pe_kernel(float* __restrict__ PE) {
    const int idx = blockIdx.x * 256 + threadIdx.x;
    const int t = idx >> 8, p = idx & 255;
    const float fr = expf((float)(2 * p) * -0.017988946039015984f);
    const float arg = (float)t * fr;
    float s, c;
    sincosf(arg, &s, &c);
    float2 v = {s, c};
    *(float2*)&PE[(size_t)t * 512 + 2 * p] = v;
}

// ---------------------------------------------------------------------------
// Flash attention (unchanged from round 7).
// ---------------------------------------------------------------------------
__global__ __launch_bounds__(256) void attn_kernel(
    const u16* __restrict__ QKV, u16* __restrict__ CTX, const int* __restrict__ obs,
    float* __restrict__ PBm, float* __restrict__ PBl, float* __restrict__ PBo)
{
    __shared__ u16 Ks[64 * 64];
    __shared__ u16 Vt[64 * 64];
    __shared__ u16 Ps[4][16 * 64];
    const int b = blockIdx.z, h = blockIdx.y;
    const int L = obs[b];
    const int tid = threadIdx.x, w = tid >> 6, l = tid & 63;
    const size_t tb = (size_t)b * 2048;

    if (blockIdx.x >= 32) {
        const int cbase = (blockIdx.x - 32) * 4;
        if (cbase * 64 > L) return;
        const int cc = cbase + w;
        float* pP = (float*)Ks;
        u16 q16[64];
        #pragma unroll
        for (int dd = 0; dd < 8; ++dd)
            *(uint4*)&q16[dd * 8] = *(const uint4*)&QKV[(tb + L) * 1536 + h * 64 + dd * 8];
        const int j = cc * 64 + l;
        const bool val = (j <= L);
        float s = -3.0e38f;
        if (val) {
            s = 0.f;
            const u16* kp = &QKV[(tb + j) * 1536 + 512 + h * 64];
            #pragma unroll
            for (int dd = 0; dd < 8; ++dd) {
                uint4 kk = *(const uint4*)&kp[dd * 8];
                const u16* ke = (const u16*)&kk;
                #pragma unroll
                for (int e = 0; e < 8; ++e)
                    s += bf2f(q16[dd * 8 + e]) * bf2f(ke[e]);
            }
            s *= 0.125f;
        }
        float mx = s;
        #pragma unroll
        for (int d = 1; d < 64; d <<= 1) mx = fmaxf(mx, __shfl_xor(mx, d, 64));
        const float p = val ? __expf(s - mx) : 0.f;
        float ps = p;
        #pragma unroll
        for (int d = 1; d < 64; d <<= 1) ps += __shfl_xor(ps, d, 64);
        pP[w * 64 + l] = p;
        __builtin_amdgcn_wave_barrier();
        if (cc * 64 <= L) {
            float oacc = 0.f;
            #pragma unroll 4
            for (int jj = 0; jj < 64; ++jj) {
                const int key = cc * 64 + jj;
                const int rr = (key <= L) ? key : L;
                oacc += pP[w * 64 + jj] * bf2f(QKV[(tb + rr) * 1536 + 1024 + h * 64 + l]);
            }
            const int pidx = (b * 8 + h) * 32 + cc;
            PBo[(size_t)pidx * 64 + l] = oacc;
            if (l == 0) { PBm[pidx] = mx; PBl[pidx] = ps; }
        }
        return;
    }

    const int i0 = blockIdx.x * 64;
    if (i0 > L) return;

    bf16x8 qa0, qa1;
    {
        const int qrow = i0 + 16 * w + (l & 15);
        const u16* qp = &QKV[(tb + qrow) * 1536 + h * 64];
        qa0 = *(const bf16x8*)(qp + 8 * (l >> 4));
        qa1 = *(const bf16x8*)(qp + 32 + 8 * (l >> 4));
    }
    const int g0 = (l >> 4) ^ (l & 7);
    const int g1 = ((l >> 4) + 4) ^ (l & 7);

    float m_r[4] = {-1e30f, -1e30f, -1e30f, -1e30f};
    float l_r[4] = {0.f, 0.f, 0.f, 0.f};
    f32x4 acc_o[4] = {};
    const int klo = (i0 >= 128) ? (i0 - 64) : 0;
    int khi = (L < klo) ? klo : min(i0 + 63, L);

    for (int j0 = klo; j0 <= khi; j0 += 64) {
        __syncthreads();
        {
            const int krow0 = 8 * w + (l >> 3);
            const int kswz = ((l & 7) ^ (l >> 3)) << 3;
            #pragma unroll
            for (int q = 0; q < 2; ++q) {
                const int row = krow0 + 32 * q;
                g2lds16(&QKV[(tb + j0 + row) * 1536 + 512 + h * 64 + kswz],
                        &Ks[(8 * w + 32 * q) * 64]);
            }
            const int vr = tid >> 3, c8 = (tid & 7) * 8;
            #pragma unroll
            for (int q = 0; q < 2; ++q) {
                const int row = vr + 32 * q;
                uint4 vv = *(const uint4*)&QKV[(tb + j0 + row) * 1536 + 1024 + h * 64 + c8];
                const u16* vs = (const u16*)&vv;
                #pragma unroll
                for (int e = 0; e < 8; ++e) {
                    const int d = c8 + e;
                    Vt[d * 64 + (((row >> 3) ^ e) << 3) + (row & 7)] = vs[e];
                }
            }
        }
        __syncthreads();
        f32x4 s[4];
        #pragma unroll
        for (int f = 0; f < 4; ++f) {
            f32x4 z = {0.f, 0.f, 0.f, 0.f};
            const int rowk = (f * 16 + (l & 15)) * 64;
            bf16x8 kb0 = *(const bf16x8*)&Ks[rowk + g0 * 8];
            bf16x8 kb1 = *(const bf16x8*)&Ks[rowk + g1 * 8];
            z = MFMA16(qa0, kb0, z);
            z = MFMA16(qa1, kb1, z);
            s[f] = z;
        }
        float pm[4];
        #pragma unroll
        for (int r = 0; r < 4; ++r) {
            const int i_r = i0 + 16 * w + (l >> 4) * 4 + r;
            float mx = -__builtin_inff();
            #pragma unroll
            for (int f = 0; f < 4; ++f) {
                const int j = j0 + f * 16 + (l & 15);
                float sv = s[f][r] * 0.125f;
                const bool ok = (i_r >= L) ? (j == klo)
                              : (j <= i_r && (i_r <= 64 || j >= i_r - 64));
                sv = ok ? sv : -__builtin_inff();
                s[f][r] = sv;
                mx = fmaxf(mx, sv);
            }
            pm[r] = mx;
        }
        #pragma unroll
        for (int d = 1; d < 16; d <<= 1)
            #pragma unroll
            for (int r = 0; r < 4; ++r) pm[r] = fmaxf(pm[r], __shfl_xor(pm[r], d, 64));
        float sc[4];
        #pragma unroll
        for (int r = 0; r < 4; ++r) {
            const float mn = fmaxf(m_r[r], fmaxf(pm[r], -1e30f));
            sc[r] = __expf(m_r[r] - mn);
            m_r[r] = mn;
            l_r[r] *= sc[r];
        }
        #pragma unroll
        for (int f = 0; f < 4; ++f)
            #pragma unroll
            for (int r = 0; r < 4; ++r) acc_o[f][r] *= sc[r];
        float ps[4] = {0.f, 0.f, 0.f, 0.f};
        #pragma unroll
        for (int f = 0; f < 4; ++f)
            #pragma unroll
            for (int r = 0; r < 4; ++r) {
                const float p = __expf(s[f][r] - m_r[r]);
                s[f][r] = p;
                ps[r] += p;
            }
        #pragma unroll
        for (int d = 1; d < 16; d <<= 1)
            #pragma unroll
            for (int r = 0; r < 4; ++r) ps[r] += __shfl_xor(ps[r], d, 64);
        #pragma unroll
        for (int r = 0; r < 4; ++r) l_r[r] += ps[r];
        {
            const int cg = ((l >> 3) & 1);
            #pragma unroll
            for (int f = 0; f < 4; ++f)
                #pragma unroll
                for (int r = 0; r < 4; ++r) {
                    const int prow = (l >> 4) * 4 + r;
                    Ps[w][prow * 64 + (((f * 2 + cg) ^ (prow & 7)) << 3) + (l & 7)] =
                        f2bf(s[f][r]);
                }
        }
        bf16x8 pa0 = *(const bf16x8*)&Ps[w][(l & 15) * 64 + g0 * 8];
        bf16x8 pa1 = *(const bf16x8*)&Ps[w][(l & 15) * 64 + g1 * 8];
        #pragma unroll
        for (int f = 0; f < 4; ++f) {
            const int dv = (f * 16 + (l & 15)) * 64;
            bf16x8 vb0 = *(const bf16x8*)&Vt[dv + g0 * 8];
            bf16x8 vb1 = *(const bf16x8*)&Vt[dv + g1 * 8];
            acc_o[f] = MFMA16(pa0, vb0, acc_o[f]);
            acc_o[f] = MFMA16(pa1, vb1, acc_o[f]);
        }
    }
    #pragma unroll
    for (int r = 0; r < 4; ++r) {
        const float inv = 1.f / l_r[r];
        const int row = i0 + 16 * w + (l >> 4) * 4 + r;
        if (row != L) {
            #pragma unroll
            for (int f = 0; f < 4; ++f)
                CTX[(tb + row) * 512 + h * 64 + f * 16 + (l & 15)] = f2bf(acc_o[f][r] * inv);
        }
    }
}

__global__ void attn_merge(const float* __restrict__ PBm, const float* __restrict__ PBl,
                           const float* __restrict__ PBo, u16* __restrict__ CTX,
                           const int* __restrict__ obs)
{
    const int h = blockIdx.x, b = blockIdx.y, l = threadIdx.x;
    const int L = obs[b];
    const int nc = (L >> 6) + 1;
    const int base = (b * 8 + h) * 32;
    float m = -3.0e38f;
    for (int c = 0; c < nc; ++c) m = fmaxf(m, PBm[base + c]);
    float lt = 0.f, ot = 0.f;
    for (int c = 0; c < nc; ++c) {
        const float sc = __expf(PBm[base + c] - m);
        lt += sc * PBl[base + c];
        ot += sc * PBo[(size_t)(base + c) * 64 + l];
    }
    CTX[((size_t)b * 2048 + L) * 512 + h * 64 + l] = f2bf(ot / lt);
}

// ---------------------------------------------------------------------------
__global__ __launch_bounds__(256) void ln_kernel(
    const float* __restrict__ Y, const float* __restrict__ gw,
    const float* __restrict__ bw, float* __restrict__ X, u16* __restrict__ Xb,
    const int* __restrict__ obs)
{
    const int tok0 = blockIdx.x * 4;
    if ((tok0 & 2047) > obs[tok0 >> 11]) return;
    const int tok = tok0 + (threadIdx.x >> 6);
    const int l = threadIdx.x & 63;
    const float* y = &Y[(size_t)tok * 512 + l * 8];
    f32x4 v0 = *(const f32x4*)y;
    f32x4 v1 = *(const f32x4*)(y + 4);
    float s = 0.f, sq = 0.f;
    #pragma unroll
    for (int e = 0; e < 4; ++e) {
        s += v0[e] + v1[e];
        sq += v0[e] * v0[e] + v1[e] * v1[e];
    }
    #pragma unroll
    for (int d = 1; d < 64; d <<= 1) {
        s += __shfl_xor(s, d, 64);
        sq += __shfl_xor(sq, d, 64);
    }
    const float mean = s * (1.f / 512.f);
    const float var = sq * (1.f / 512.f) - mean * mean;
    const float rstd = rsqrtf(var + 1e-5f);
    f32x4 o0, o1;
    union { u16 us[8]; uint4 u4; } pk;
    #pragma unroll
    for (int e = 0; e < 8; ++e) {
        const int d = l * 8 + e;
        const float xv = (e < 4) ? v0[e] : v1[e - 4];
        const float ov = (xv - mean) * rstd * gw[d] + bw[d];
        if (e < 4) o0[e] = ov; else o1[e - 4] = ov;
        pk.us[e] = f2bf(ov);
    }
    float* xo = &X[(size_t)tok * 512 + l * 8];
    *(f32x4*)xo = o0;
    *(f32x4*)(xo + 4) = o1;
    *(uint4*)&Xb[(size_t)tok * 512 + l * 8] = pk.u4;
}

__global__ void cast_bf16_kernel(const float* __restrict__ in, u16* __restrict__ out, int n) {
    const int i = (blockIdx.x * 256 + threadIdx.x) * 4;
    if (i + 3 < n) {
        f32x4 v = *(const f32x4*)&in[i];
        union { u16 us[4]; uint2 u2; } pk;
        #pragma unroll
        for (int e = 0; e < 4; ++e) pk.us[e] = f2bf(v[e]);
        *(uint2*)&out[i] = pk.u2;
    }
}

__global__ void transpose_cast(const float* __restrict__ W, u16* __restrict__ WT, int K, int N) {
    __shared__ float t[32][33];
    const int n0 = blockIdx.x * 32, k0 = blockIdx.y * 32;
    const int tx = threadIdx.x, ty = threadIdx.y;
    #pragma unroll
    for (int r = 0; r < 32; r += 8)
        t[ty + r][tx] = W[(size_t)(k0 + ty + r) * N + n0 + tx];
    __syncthreads();
    #pragma unroll
    for (int r = 0; r < 32; r += 8)
        WT[(size_t)(n0 + ty + r) * K + k0 + tx] = f2bf(t[tx][ty + r]);
}

struct WPack { const float* src[16]; u16* dst[16]; };
__global__ void transpose_all(WPack p) {
    __shared__ float t[32][33];
    int id = blockIdx.x;
    const int lyr = id / 3072;
    id -= lyr * 3072;
    int wi, K, N;
    if (id < 768)       { wi = 0; K = 512;  N = 1536; }
    else if (id < 1024) { wi = 1; K = 512;  N = 512;  id -= 768; }
    else if (id < 2048) { wi = 2; K = 512;  N = 2048; id -= 1024; }
    else                { wi = 3; K = 2048; N = 512;  id -= 2048; }
    const float* W = p.src[lyr * 4 + wi];
    u16* D = p.dst[lyr * 4 + wi];
    const int nx = N >> 5;
    const int n0 = (id % nx) * 32, k0 = (id / nx) * 32;
    const int tx = threadIdx.x, ty = threadIdx.y;
    #pragma unroll
    for (int r = 0; r < 32; r += 8)
        t[ty + r][tx] = W[(size_t)(k0 + ty + r) * N + n0 + tx];
    __syncthreads();
    #pragma unroll
    for (int r = 0; r < 32; r += 8)
        D[(size_t)(n0 + ty + r) * K + k0 + tx] = f2bf(t[tx][ty + r]);
}

__global__ void agg_partial(const float* __restrict__ X, float* __restrict__ part,
                            const int* __restrict__ obs) {
    const int b = blockIdx.y, c = blockIdx.x, d = threadIdx.x;
    const int L = obs[b];
    float s = 0.f;
    const int t0 = c * 128;
    int tend = t0 + 128;
    if (tend > L + 1) tend = L + 1;
    for (int t = t0; t < tend; ++t) s += X[((size_t)b * 2048 + t) * 512 + d];
    part[((size_t)b * 16 + c) * 512 + d] = s;
}

__global__ void agg_final(const float* __restrict__ part, float* __restrict__ out,
                          const int* __restrict__ obs) {
    const int b = blockIdx.x, d = threadIdx.x;
    float s = 0.f;
    #pragma unroll
    for (int c = 0; c < 16; ++c) s += part[((size_t)b * 16 + c) * 512 + d];
    out[b * 512 + d] = s / (float)(obs[b] + 1);
}

// ---------------------------------------------------------------------------
// Workspace: big path ~257 MB (gated ws_size>=270MB), small path ~233 MB
// (proven in rounds 4-7).
// ---------------------------------------------------------------------------
extern "C" void kernel_launch(void* const* d_in, const int* in_sizes, int n_in,
                              void* d_out, int out_size, void* d_ws, size_t ws_size,
                              hipStream_t stream)
{
    const int M = 32768;        // B*T
    const int FCH = 16384;      // FF chunk rows (small-ws path)
    const bool bigws = ws_size >= (size_t)270 * 1024 * 1024;
    const float* traj = (const float*)d_in[0];
    const int* obs = (const int*)d_in[1];
    const float* w_in = (const float*)d_in[2];
    const float* b_in = (const float*)d_in[3];

    char* base = (char*)d_ws;
    size_t off = 0;
    auto carve = [&](size_t bytes) -> void* {
        void* p = base + off;
        off += (bytes + 255) & ~(size_t)255;
        return p;
    };
    u16* U     = (u16*)carve((size_t)M * (bigws ? 2048 : 1536) * 2);
    u16* Xb    = (u16*)carve((size_t)M * 512 * 2);
    float* X   = (float*)carve((size_t)M * 512 * 4);
    float* PE  = (float*)carve((size_t)2048 * 512 * 4);
    float* PBm = (float*)carve((size_t)16 * 8 * 32 * 4);
    float* PBl = (float*)carve((size_t)16 * 8 * 32 * 4);
    float* PBo = (float*)carve((size_t)16 * 8 * 32 * 64 * 4);
    float* part = (float*)carve((size_t)16 * 16 * 512 * 4);
    u16* wTin  = (u16*)carve((size_t)512 * 512 * 2);
    u16 *wqkv[4], *wo[4], *wff1[4], *wff2[4];
    for (int l = 0; l < 4; ++l) {
        wqkv[l] = (u16*)carve((size_t)1536 * 512 * 2);
        wo[l]   = (u16*)carve((size_t)512 * 512 * 2);
        wff1[l] = (u16*)carve((size_t)2048 * 512 * 2);
        wff2[l] = (u16*)carve((size_t)512 * 2048 * 2);
    }

    dim3 tb32(32, 8);
    pe_kernel<<<2048, 256, 0, stream>>>(PE);
    transpose_cast<<<dim3(16, 16), tb32, 0, stream>>>(w_in, wTin, 512, 512);
    {
        WPack p;
        for (int l = 0; l < 4; ++l) {
            const int bi = 4 + 12 * l;
            p.src[l * 4 + 0] = (const float*)d_in[bi + 0];
            p.src[l * 4 + 1] = (const float*)d_in[bi + 2];
            p.src[l * 4 + 2] = (const float*)d_in[bi + 4];
            p.src[l * 4 + 3] = (const float*)d_in[bi + 6];
            p.dst[l * 4 + 0] = wqkv[l];
            p.dst[l * 4 + 1] = wo[l];
            p.dst[l * 4 + 2] = wff1[l];
            p.dst[l * 4 + 3] = wff2[l];
        }
        transpose_all<<<12288, tb32, 0, stream>>>(p);
    }

    cast_bf16_kernel<<<(M * 512) / 1024, 256, 0, stream>>>(traj, U, M * 512);
    gemm_bf16<0, 64><<<dim3(4, M / 128), 256, 0, stream>>>(
        U, wTin, b_in, X, Xb, PE, obs, M, 512, 512);

    for (int lyr = 0; lyr < 4; ++lyr) {
        const int bi = 4 + 12 * lyr;
        const float* b_qkv = (const float*)d_in[bi + 1];
        const float* b_o   = (const float*)d_in[bi + 3];
        const float* b_ff1 = (const float*)d_in[bi + 5];
        const float* b_ff2 = (const float*)d_in[bi + 7];
        const float* ln1g  = (const float*)d_in[bi + 8];
        const float* ln1b  = (const float*)d_in[bi + 9];
        const float* ln2g  = (const float*)d_in[bi + 10];
        const float* ln2b  = (const float*)d_in[bi + 11];

        gemm_bf16<1, 32><<<dim3(12, M / 128), 256, 0, stream>>>(
            Xb, wqkv[lyr], b_qkv, nullptr, U, nullptr, obs, M, 1536, 512);
        attn_kernel<<<dim3(40, 8, 16), 256, 0, stream>>>(U, Xb, obs, PBm, PBl, PBo);
        attn_merge<<<dim3(8, 16), 64, 0, stream>>>(PBm, PBl, PBo, Xb, obs);
        gemm_bf16<2, 64><<<dim3(4, M / 128), 256, 0, stream>>>(
            Xb, wo[lyr], b_o, X, nullptr, X, obs, M, 512, 512);
        ln_kernel<<<M / 4, 256, 0, stream>>>(X, ln1g, ln1b, X, Xb, obs);
        if (bigws) {
            gemm_bf16<3, 32><<<dim3(16, M / 128), 256, 0, stream>>>(
                Xb, wff1[lyr], b_ff1, nullptr, U, nullptr, obs, M, 2048, 512);
            gemm_bf16<2, 64><<<dim3(4, M / 128), 256, 0, stream>>>(
                U, wff2[lyr], b_ff2, X, nullptr, X, obs, M, 512, 2048);
        } else {
            for (int c = 0; c < 2; ++c) {
                gemm_bf16<3, 32><<<dim3(16, FCH / 128), 256, 0, stream>>>(
                    Xb + (size_t)c * FCH * 512, wff1[lyr], b_ff1, nullptr, U, nullptr,
                    obs + c * 8, FCH, 2048, 512);
                gemm_bf16<2, 64><<<dim3(4, FCH / 128), 256, 0, stream>>>(
                    U, wff2[lyr], b_ff2, X + (size_t)c * FCH * 512, nullptr,
                    X + (size_t)c * FCH * 512, obs + c * 8, FCH, 512, 2048);
            }
        }
        ln_kernel<<<M / 4, 256, 0, stream>>>(X, ln2g, ln2b, X, Xb, obs);
    }

    agg_partial<<<dim3(16, 16), 512, 0, stream>>>(X, part, obs);
    agg_final<<<16, 512, 0, stream>>>(part, (float*)d_out, obs);
}